// Round 7
// baseline (271.228 us; speedup 1.0000x reference)
//
#include <hip/hip_runtime.h>
#include <hip/hip_bf16.h>

#define NN   100000
#define C0   40000
#define C1   30000
#define C2   30000
#define HID  64
#define KK   8
#define EE   1600000
#define DIN  512
#define NCLS 16
#define NB   196      // coarse dst buckets == node chunks (512 each)
#define BKE  2048     // edges per block in coarse pass
#define GR1  782      // ceil(EE/BKE)
#define NBC  1568     // KK*NB node-bucket counts
#define MAXT 1571     // upper bound on op-GEMM tiles
#define FCT  469      // ceil(30000/64) fc tiles per segment
#define GNT  1563     // ceil(100000/64) gnn tiles
#define AP   88       // LDS row pitch (bf16 units) for pre_mfma

typedef unsigned short ushortT;
typedef __attribute__((ext_vector_type(8))) short bf16x8;
typedef __attribute__((ext_vector_type(4))) float f32x4;

__device__ __forceinline__ float b2f(ushortT u) {
    return __uint_as_float((unsigned)u << 16);
}
__device__ __forceinline__ ushortT f2b(float x) {
    unsigned v = __float_as_uint(x);
    unsigned r = (v + 0x7FFF + ((v >> 16) & 1)) >> 16;   // RNE
    return (ushortT)r;
}
__device__ __forceinline__ unsigned pk2(float lo, float hi) {
    return (unsigned)f2b(lo) | ((unsigned)f2b(hi) << 16);
}

// ================ K1: bucket_count + nb_count + wt_conv (merged) ================
__global__ __launch_bounds__(256) void setup_k(const int* __restrict__ dst,
                                               const int* __restrict__ na,
                                               const float* __restrict__ W,
                                               int* __restrict__ bcnt,
                                               int* __restrict__ nbc,
                                               ushortT* __restrict__ WT) {
    __shared__ int sh[NB];
    const int t = threadIdx.x, b = blockIdx.x;
    if (b < GR1) {
        for (int i = t; i < NB; i += 256) sh[i] = 0;
        __syncthreads();
        const int base = b * BKE;
        for (int u = 0; u < BKE / 256; ++u) {
            int e = base + t + u * 256;
            if (e < EE) atomicAdd(&sh[dst[e] >> 9], 1);
        }
        __syncthreads();
        for (int i = t; i < NB; i += 256) {
            int c = sh[i];
            if (c) atomicAdd(&bcnt[i], c);
        }
    } else if (b < GR1 + NB) {
        const int nb_ = b - GR1;
        if (t < KK) sh[t] = 0;
        __syncthreads();
        #pragma unroll
        for (int u = 0; u < 2; ++u) {
            int n = nb_ * 512 + t + u * 256;
            if (n < NN) atomicAdd(&sh[na[n]], 1);
        }
        __syncthreads();
        if (t < KK) nbc[t * NB + nb_] = sh[t];
    } else {
        int idx = (b - GR1 - NB) * 256 + t;   // 0..4095
        int c = idx >> 6, k8 = (idx & 63) * 8;
        uint4 v;
        v.x = pk2(W[(size_t)(k8 + 0) * HID + c], W[(size_t)(k8 + 1) * HID + c]);
        v.y = pk2(W[(size_t)(k8 + 2) * HID + c], W[(size_t)(k8 + 3) * HID + c]);
        v.z = pk2(W[(size_t)(k8 + 4) * HID + c], W[(size_t)(k8 + 5) * HID + c]);
        v.w = pk2(W[(size_t)(k8 + 6) * HID + c], W[(size_t)(k8 + 7) * HID + c]);
        *(uint4*)(WT + (size_t)c * DIN + k8) = v;
    }
}

// ================ pre GEMM via MFMA ================
__global__ __launch_bounds__(256) void pre_mfma(const float* __restrict__ A,
                                                const ushortT* __restrict__ WT,
                                                const float* __restrict__ b,
                                                ushortT* __restrict__ hb) {
    __shared__ ushortT Ak[2][64 * AP];
    __shared__ ushortT Bk[2][64 * AP];
    const int tid = threadIdx.x;
    const int row0 = blockIdx.x * 64;
    const int rr = tid >> 2, q = tid & 3;
    const int w = tid >> 6, l = tid & 63;
    const int lr = l & 15, g = l >> 4;
    f32x4 acc[4] = {{0.f,0.f,0.f,0.f},{0.f,0.f,0.f,0.f},{0.f,0.f,0.f,0.f},{0.f,0.f,0.f,0.f}};
    float4 av0, av1, av2, av3;
    uint4 bv0, bv1;
    {
        const float* ap = A + (size_t)(row0 + rr) * DIN + q * 16;
        av0 = *(const float4*)(ap + 0);  av1 = *(const float4*)(ap + 4);
        av2 = *(const float4*)(ap + 8);  av3 = *(const float4*)(ap + 12);
        const uint4* bp = (const uint4*)(WT + (size_t)rr * DIN + q * 16);
        bv0 = bp[0]; bv1 = bp[1];
    }
    {
        uint4 ua0, ua1;
        ua0.x = pk2(av0.x, av0.y); ua0.y = pk2(av0.z, av0.w);
        ua0.z = pk2(av1.x, av1.y); ua0.w = pk2(av1.z, av1.w);
        ua1.x = pk2(av2.x, av2.y); ua1.y = pk2(av2.z, av2.w);
        ua1.z = pk2(av3.x, av3.y); ua1.w = pk2(av3.z, av3.w);
        *(uint4*)&Ak[0][rr * AP + q * 16] = ua0;
        *(uint4*)&Ak[0][rr * AP + q * 16 + 8] = ua1;
        *(uint4*)&Bk[0][rr * AP + q * 16] = bv0;
        *(uint4*)&Bk[0][rr * AP + q * 16 + 8] = bv1;
    }
    __syncthreads();
    for (int t = 0; t < 8; ++t) {
        if (t < 7) {
            const int k0 = (t + 1) * 64;
            const float* ap = A + (size_t)(row0 + rr) * DIN + k0 + q * 16;
            av0 = *(const float4*)(ap + 0);  av1 = *(const float4*)(ap + 4);
            av2 = *(const float4*)(ap + 8);  av3 = *(const float4*)(ap + 12);
            const uint4* bp = (const uint4*)(WT + (size_t)rr * DIN + k0 + q * 16);
            bv0 = bp[0]; bv1 = bp[1];
        }
        const int bu = t & 1;
        #pragma unroll
        for (int s = 0; s < 2; ++s) {
            bf16x8 af = *(const bf16x8*)&Ak[bu][(w * 16 + lr) * AP + s * 32 + g * 8];
            #pragma unroll
            for (int n = 0; n < 4; ++n) {
                bf16x8 bf = *(const bf16x8*)&Bk[bu][(n * 16 + lr) * AP + s * 32 + g * 8];
                acc[n] = __builtin_amdgcn_mfma_f32_16x16x32_bf16(af, bf, acc[n], 0, 0, 0);
            }
        }
        if (t < 7) {
            const int nb = (t + 1) & 1;
            uint4 ua0, ua1;
            ua0.x = pk2(av0.x, av0.y); ua0.y = pk2(av0.z, av0.w);
            ua0.z = pk2(av1.x, av1.y); ua0.w = pk2(av1.z, av1.w);
            ua1.x = pk2(av2.x, av2.y); ua1.y = pk2(av2.z, av2.w);
            ua1.z = pk2(av3.x, av3.y); ua1.w = pk2(av3.z, av3.w);
            *(uint4*)&Ak[nb][rr * AP + q * 16] = ua0;
            *(uint4*)&Ak[nb][rr * AP + q * 16 + 8] = ua1;
            *(uint4*)&Bk[nb][rr * AP + q * 16] = bv0;
            *(uint4*)&Bk[nb][rr * AP + q * 16 + 8] = bv1;
        }
        __syncthreads();
    }
    #pragma unroll
    for (int n = 0; n < 4; ++n) {
        float bb = b[n * 16 + lr];
        #pragma unroll
        for (int i = 0; i < 4; ++i) {
            int row = row0 + w * 16 + g * 4 + i;
            hb[(size_t)row * HID + n * 16 + lr] = f2b(acc[n][i] + bb);
        }
    }
}

// ================ K3: bucket_scan + nb_scan (merged) ================
__global__ __launch_bounds__(256) void scan_k(const int* __restrict__ bcnt,
                                              int* __restrict__ bbase,
                                              int* __restrict__ bcur,
                                              int* __restrict__ offs,
                                              const int* __restrict__ nbc,
                                              int* __restrict__ gbase,
                                              int* __restrict__ koff,
                                              int* __restrict__ tmap_b,
                                              int* __restrict__ tmap_s) {
    const int t = threadIdx.x;
    if (blockIdx.x == 0) {
        if (t == 0) {
            int run = 0;
            for (int i = 0; i < NB; ++i) { bbase[i] = run; bcur[i] = run; run += bcnt[i]; }
            offs[NN] = EE;
        }
        return;
    }
    // nb_scan
    __shared__ int sm[256];
    __shared__ int carry;
    __shared__ int tl[KK];
    if (t == 0) carry = 0;
    for (int i = t; i < MAXT; i += 256) tmap_b[i] = -1;
    __syncthreads();
    for (int c = 0; c < 7; ++c) {
        int i = c * 256 + t;
        int v = (i < NBC) ? nbc[i] : 0;
        sm[t] = v;
        __syncthreads();
        for (int off = 1; off < 256; off <<= 1) {
            int y = (t >= off) ? sm[t - off] : 0;
            __syncthreads();
            sm[t] += y;
            __syncthreads();
        }
        int base = carry;
        int excl = base + sm[t] - v;
        if (i < NBC) {
            gbase[i] = excl;
            if ((i % NB) == 0) koff[i / NB] = excl;
        }
        __syncthreads();
        if (t == 255) carry = base + sm[255];
        __syncthreads();
    }
    if (t == 0) {
        koff[KK] = NN;
        int run = 0;
        for (int k = 0; k < KK; ++k) {
            tl[k] = run;
            int cnt = ((k == KK - 1) ? NN : koff[k + 1]) - koff[k];
            run += (cnt + 63) / 64;
        }
    }
    __syncthreads();
    if (t < KK) {
        int k = t;
        int kb = koff[k];
        int ke = (k == KK - 1) ? NN : koff[k + 1];
        int nt = (ke - kb + 63) / 64;
        for (int tt = 0; tt < nt; ++tt) {
            tmap_b[tl[k] + tt] = k;
            tmap_s[tl[k] + tt] = kb + tt * 64;
        }
    }
}

// ================ K4: coarse_scatter + nb_scatter (merged) ================
__global__ __launch_bounds__(256) void scatter_k(const int* __restrict__ src,
                                                 const int* __restrict__ dst,
                                                 int* __restrict__ bcur,
                                                 uint2* __restrict__ ebuf,
                                                 const int* __restrict__ na,
                                                 const int* __restrict__ gbase,
                                                 int* __restrict__ perm) {
    __shared__ int s1[NB];
    __shared__ int s2[NB];
    const int t = threadIdx.x, b = blockIdx.x;
    if (b < GR1) {
        for (int i = t; i < NB; i += 256) s1[i] = 0;
        __syncthreads();
        const int base = b * BKE;
        int mys[8], myd[8], mybin[8], myrank[8];
        #pragma unroll
        for (int u = 0; u < 8; ++u) {
            int e = base + t + u * 256;
            if (e < EE) {
                int d = dst[e];
                mys[u] = src[e]; myd[u] = d; mybin[u] = d >> 9;
                myrank[u] = atomicAdd(&s1[mybin[u]], 1);
            } else mybin[u] = -1;
        }
        __syncthreads();
        for (int i = t; i < NB; i += 256) {
            int c = s1[i];
            s2[i] = c ? atomicAdd(&bcur[i], c) : 0;
        }
        __syncthreads();
        #pragma unroll
        for (int u = 0; u < 8; ++u) {
            if (mybin[u] >= 0) {
                uint2 e; e.x = (unsigned)mys[u]; e.y = (unsigned)myd[u];
                ebuf[s2[mybin[u]] + myrank[u]] = e;
            }
        }
    } else {
        const int nb_ = b - GR1;
        if (t < KK) { s1[t] = 0; s2[t] = gbase[t * NB + nb_]; }
        __syncthreads();
        #pragma unroll
        for (int u = 0; u < 2; ++u) {
            int n = nb_ * 512 + t + u * 256;
            if (n < NN) {
                int k = na[n];
                int r = atomicAdd(&s1[k], 1);
                perm[s2[k] + r] = n;
            }
        }
    }
}

// ================ r2: per-bucket exact CSR ================
__global__ __launch_bounds__(256) void fine_scatter(const uint2* __restrict__ ebuf,
                                                    const int* __restrict__ bbase,
                                                    const int* __restrict__ bend,
                                                    int* __restrict__ offs,
                                                    int* __restrict__ split,
                                                    int* __restrict__ ssrc) {
    __shared__ int hist[1024];
    __shared__ int lofs[1024];
    __shared__ int sm[256];
    const int t = threadIdx.x, b = blockIdx.x;
    const int beg = bbase[b], end = bend[b];
    for (int i = t; i < 1024; i += 256) hist[i] = 0;
    __syncthreads();
    for (int j = beg + t; j < end; j += 256) {
        uint2 e = ebuf[j];
        int bin = ((e.y & 511) << 1) | (e.x < C0 ? 0 : 1);
        atomicAdd(&hist[bin], 1);
    }
    __syncthreads();
    int v0 = hist[4 * t], v1 = hist[4 * t + 1], v2 = hist[4 * t + 2], v3 = hist[4 * t + 3];
    int ts = v0 + v1 + v2 + v3;
    sm[t] = ts;
    __syncthreads();
    for (int off = 1; off < 256; off <<= 1) {
        int y = (t >= off) ? sm[t - off] : 0;
        __syncthreads();
        sm[t] += y;
        __syncthreads();
    }
    int pre = sm[t] - ts;
    lofs[4 * t] = pre; lofs[4 * t + 1] = pre + v0;
    lofs[4 * t + 2] = pre + v0 + v1; lofs[4 * t + 3] = pre + v0 + v1 + v2;
    __syncthreads();
    const int d0 = b * 512;
    for (int i = t; i < 512; i += 256) {
        int n = d0 + i;
        if (n < NN) {
            offs[n]  = beg + lofs[2 * i];
            split[n] = beg + lofs[2 * i + 1];
        }
    }
    __syncthreads();
    for (int j = beg + t; j < end; j += 256) {
        uint2 e = ebuf[j];
        int bin = ((e.y & 511) << 1) | (e.x < C0 ? 0 : 1);
        int pos = beg + atomicAdd(&lofs[bin], 1);
        ssrc[pos] = (int)e.x;
    }
}

// ================ shared 64x64x64 GEMM core ================
__device__ __forceinline__ void gemm64(const float As[64][65], const float Bs[64][64],
                                       float acc[4][4], int tx, int ty) {
    for (int kk = 0; kk < 64; ++kk) {
        float a0 = As[ty * 4 + 0][kk], a1 = As[ty * 4 + 1][kk];
        float a2 = As[ty * 4 + 2][kk], a3 = As[ty * 4 + 3][kk];
        float4 bv = *(const float4*)(&Bs[kk][tx * 4]);
        acc[0][0] += a0 * bv.x; acc[0][1] += a0 * bv.y; acc[0][2] += a0 * bv.z; acc[0][3] += a0 * bv.w;
        acc[1][0] += a1 * bv.x; acc[1][1] += a1 * bv.y; acc[1][2] += a1 * bv.z; acc[1][3] += a1 * bv.w;
        acc[2][0] += a2 * bv.x; acc[2][1] += a2 * bv.y; acc[2][2] += a2 * bv.z; acc[2][3] += a2 * bv.w;
        acc[3][0] += a3 * bv.x; acc[3][1] += a3 * bv.y; acc[3][2] += a3 * bv.z; acc[3][3] += a3 * bv.w;
    }
}

// gather one node's row-sum into float4 (valid in sub==0 lanes after shfl reduce)
__device__ __forceinline__ float4 gather32(const ushortT* __restrict__ rows,
                                           const int* __restrict__ ssrc,
                                           int beg, int ge, int sub, int c4) {
    float4 a0 = {0.f,0.f,0.f,0.f}, a1 = {0.f,0.f,0.f,0.f};
    int j = beg + sub;
    for (; j + 2 < ge; j += 4) {
        int s0 = ssrc[j], s1 = ssrc[j + 2];
        ushort4 u = *(const ushort4*)(rows + (size_t)s0 * HID + c4 * 4);
        ushort4 v = *(const ushort4*)(rows + (size_t)s1 * HID + c4 * 4);
        a0.x += b2f(u.x); a0.y += b2f(u.y); a0.z += b2f(u.z); a0.w += b2f(u.w);
        a1.x += b2f(v.x); a1.y += b2f(v.y); a1.z += b2f(v.z); a1.w += b2f(v.w);
    }
    if (j < ge) {
        ushort4 u = *(const ushort4*)(rows + (size_t)ssrc[j] * HID + c4 * 4);
        a0.x += b2f(u.x); a0.y += b2f(u.y); a0.z += b2f(u.z); a0.w += b2f(u.w);
    }
    a0.x += a1.x; a0.y += a1.y; a0.z += a1.z; a0.w += a1.w;
    a0.x += __shfl_down(a0.x, 16); a0.y += __shfl_down(a0.y, 16);
    a0.z += __shfl_down(a0.z, 16); a0.w += __shfl_down(a0.w, 16);
    return a0;
}

// ================ op_fused: gather(filtered) + k-GEMM + skip/emb epilogue ================
__global__ __launch_bounds__(256) void op_fused(const ushortT* __restrict__ hb,
                                                const int* __restrict__ offs,
                                                const int* __restrict__ split,
                                                const int* __restrict__ ssrc,
                                                const int* __restrict__ perm,
                                                const int* __restrict__ koff,
                                                const int* __restrict__ tmap_b,
                                                const int* __restrict__ tmap_s,
                                                const float* __restrict__ op_W,
                                                const float* __restrict__ op_b,
                                                const float* __restrict__ emb_W,
                                                const float* __restrict__ emb_b,
                                                ushortT* __restrict__ htb) {
    __shared__ float As[64][65];
    __shared__ float Bs[64][64];
    __shared__ int idx[64];
    const int bk = tmap_b[blockIdx.x];
    if (bk < 0) return;
    const int start = tmap_s[blockIdx.x];
    const int kend = koff[bk + 1];
    const int tid = threadIdx.x;
    if (tid < 64) {
        int p = start + tid;
        idx[tid] = (p < kend) ? perm[p] : -1;
    }
    for (int i = tid; i < 64 * 16; i += 256) {
        int r = i >> 4, c4 = i & 15;
        *(float4*)(&Bs[r][c4 * 4]) = *(const float4*)(op_W + (size_t)bk * HID * HID + (size_t)r * HID + c4 * 4);
    }
    __syncthreads();
    const int nl0 = tid >> 5, sub = (tid >> 4) & 1, gc4 = tid & 15;
    for (int p = 0; p < 8; ++p) {
        const int nl = p * 8 + nl0;
        const int n = idx[nl];
        float4 r = {0.f, 0.f, 0.f, 0.f};
        float inv = 0.f;
        if (n >= 0) {
            const int beg = offs[n], sp = split[n], endf = offs[n + 1];
            r = gather32(hb, ssrc, beg, sp, sub, gc4);
            inv = 1.0f / fmaxf((float)(endf - beg), 1.0f);
        } else {
            r.x += __shfl_down(r.x, 16);   // keep lane activity symmetric (no-op)
        }
        if (sub == 0) {
            r.x *= inv; r.y *= inv; r.z *= inv; r.w *= inv;
            *(float4*)(&As[nl][gc4 * 4]) = r;
        }
    }
    __syncthreads();
    const int tx = tid & 15, ty = tid >> 4;
    float acc[4][4] = {};
    gemm64(As, Bs, acc, tx, ty);
    float4 ob = *(const float4*)(op_b + (size_t)bk * HID + tx * 4);
    #pragma unroll
    for (int rr = 0; rr < 4; ++rr) {
        int n = idx[ty * 4 + rr];
        if (n < 0) continue;
        float4 v;
        v.x = acc[rr][0] + ob.x; v.y = acc[rr][1] + ob.y;
        v.z = acc[rr][2] + ob.z; v.w = acc[rr][3] + ob.w;
        if (n < C0) {
            ushort4 hu = *(const ushort4*)(hb + (size_t)n * HID + tx * 4);
            v.x += b2f(hu.x); v.y += b2f(hu.y); v.z += b2f(hu.z); v.w += b2f(hu.w);
        } else {
            int si = (n < C0 + C1) ? 0 : 1;
            int rn = n - C0 - si * C1;
            float4 ew = *(const float4*)(emb_W + ((size_t)si * C1 + rn) * HID + tx * 4);
            float4 eb = *(const float4*)(emb_b + (size_t)si * HID + tx * 4);
            v.x += ew.x + eb.x; v.y += ew.y + eb.y;
            v.z += ew.z + eb.z; v.w += ew.w + eb.w;
        }
        ushort4 o;
        o.x = f2b(v.x); o.y = f2b(v.y); o.z = f2b(v.z); o.w = f2b(v.w);
        *(ushort4*)(htb + (size_t)n * HID + tx * 4) = o;
    }
}

// ================ fc GEMM: contiguous segment rows, in-place htb ================
__global__ __launch_bounds__(256) void fc_gemm(ushortT* __restrict__ htb,
                                               const float* __restrict__ fc_W,
                                               const float* __restrict__ fc_b) {
    __shared__ float As[64][65];
    __shared__ float Bs[64][64];
    const int si = (blockIdx.x < FCT) ? 0 : 1;
    const int t0 = blockIdx.x - si * FCT;
    const int row0 = C0 + si * C1 + t0 * 64;
    const int lim = C0 + (si + 1) * C1;
    const int tid = threadIdx.x;
    for (int i = tid; i < 64 * 16; i += 256) {
        int r = i >> 4, c4 = i & 15;
        int n = row0 + r;
        if (n < lim) {
            ushort4 u = *(const ushort4*)(htb + (size_t)n * HID + c4 * 4);
            As[r][c4 * 4 + 0] = b2f(u.x); As[r][c4 * 4 + 1] = b2f(u.y);
            As[r][c4 * 4 + 2] = b2f(u.z); As[r][c4 * 4 + 3] = b2f(u.w);
        } else {
            As[r][c4 * 4 + 0] = 0.f; As[r][c4 * 4 + 1] = 0.f;
            As[r][c4 * 4 + 2] = 0.f; As[r][c4 * 4 + 3] = 0.f;
        }
    }
    for (int i = tid; i < 64 * 16; i += 256) {
        int r = i >> 4, c4 = i & 15;
        *(float4*)(&Bs[r][c4 * 4]) = *(const float4*)(fc_W + (size_t)si * HID * HID + (size_t)r * HID + c4 * 4);
    }
    __syncthreads();
    const int tx = tid & 15, ty = tid >> 4;
    float acc[4][4] = {};
    gemm64(As, Bs, acc, tx, ty);
    float4 fb = *(const float4*)(fc_b + (size_t)si * HID + tx * 4);
    #pragma unroll
    for (int rr = 0; rr < 4; ++rr) {
        int n = row0 + ty * 4 + rr;
        if (n >= lim) continue;
        ushort4 o;
        o.x = f2b(acc[rr][0] + fb.x); o.y = f2b(acc[rr][1] + fb.y);
        o.z = f2b(acc[rr][2] + fb.z); o.w = f2b(acc[rr][3] + fb.w);
        *(ushort4*)(htb + (size_t)n * HID + tx * 4) = o;
    }
}

// ================ spmm_gnn: gather(full) + gnn GEMM + elu + logits ================
__global__ __launch_bounds__(256) void spmm_gnn(const ushortT* __restrict__ htb,
                                                const int* __restrict__ offs,
                                                const int* __restrict__ ssrc,
                                                const float* __restrict__ gnn_W,
                                                const float* __restrict__ gnn_b,
                                                const float* __restrict__ out_W,
                                                const float* __restrict__ out_b,
                                                float* __restrict__ out) {
    __shared__ float As[64][65];
    __shared__ float Bs[64][64];
    __shared__ float Wo[64 * NCLS];
    const int row0 = blockIdx.x * 64;
    const int tid = threadIdx.x;
    for (int i = tid; i < 64 * 16; i += 256) {
        int r = i >> 4, c4 = i & 15;
        *(float4*)(&Bs[r][c4 * 4]) = *(const float4*)(gnn_W + (size_t)r * HID + c4 * 4);
    }
    *(float4*)(&Wo[tid * 4]) = *(const float4*)(out_W + tid * 4);
    const int nl0 = tid >> 5, sub = (tid >> 4) & 1, gc4 = tid & 15;
    for (int p = 0; p < 8; ++p) {
        const int nl = p * 8 + nl0;
        const int n = row0 + nl;
        float4 r = {0.f, 0.f, 0.f, 0.f};
        float inv = 0.f;
        if (n < NN) {
            const int beg = offs[n], endf = offs[n + 1];
            r = gather32(htb, ssrc, beg, endf, sub, gc4);
            inv = 1.0f / fmaxf((float)(endf - beg), 1.0f);
        } else {
            r.x += __shfl_down(r.x, 16);
        }
        if (sub == 0) {
            r.x *= inv; r.y *= inv; r.z *= inv; r.w *= inv;
            *(float4*)(&As[nl][gc4 * 4]) = r;
        }
    }
    __syncthreads();
    const int tx = tid & 15, ty = tid >> 4;
    float acc[4][4] = {};
    gemm64(As, Bs, acc, tx, ty);
    __syncthreads();     // done reading As; reuse for emb
    float4 gb = *(const float4*)(gnn_b + tx * 4);
    #pragma unroll
    for (int rr = 0; rr < 4; ++rr) {
        int n = row0 + ty * 4 + rr;
        float4 v;
        v.x = acc[rr][0] + gb.x; v.y = acc[rr][1] + gb.y;
        v.z = acc[rr][2] + gb.z; v.w = acc[rr][3] + gb.w;
        v.x = (v.x > 0.f) ? v.x : expm1f(v.x);
        v.y = (v.y > 0.f) ? v.y : expm1f(v.y);
        v.z = (v.z > 0.f) ? v.z : expm1f(v.z);
        v.w = (v.w > 0.f) ? v.w : expm1f(v.w);
        As[ty * 4 + rr][tx * 4 + 0] = v.x; As[ty * 4 + rr][tx * 4 + 1] = v.y;
        As[ty * 4 + rr][tx * 4 + 2] = v.z; As[ty * 4 + rr][tx * 4 + 3] = v.w;
        if (n < NN) *(float4*)(out + (size_t)n * HID + tx * 4) = v;
    }
    __syncthreads();
    const int r = tid >> 2, cq = (tid & 3) * 4;
    float l0 = 0.f, l1 = 0.f, l2 = 0.f, l3 = 0.f;
    #pragma unroll 8
    for (int j = 0; j < 64; ++j) {
        float e = As[r][j];
        float4 w = *(const float4*)(&Wo[j * NCLS + cq]);
        l0 += e * w.x; l1 += e * w.y; l2 += e * w.z; l3 += e * w.w;
    }
    int n = row0 + r;
    if (n < NN) {
        float4 ob = *(const float4*)(out_b + cq);
        float4 lg;
        lg.x = l0 + ob.x; lg.y = l1 + ob.y; lg.z = l2 + ob.z; lg.w = l3 + ob.w;
        const size_t lbase = (size_t)NN * HID;
        *(float4*)(out + lbase + (size_t)n * NCLS + cq) = lg;
        *(float4*)(out + lbase + (size_t)NN * NCLS + (size_t)n * NCLS + cq) = lg;
    }
}

extern "C" void kernel_launch(void* const* d_in, const int* in_sizes, int n_in,
                              void* d_out, int out_size, void* d_ws, size_t ws_size,
                              hipStream_t stream) {
    const float* feats0 = (const float*)d_in[0];
    const float* W_pre  = (const float*)d_in[1];
    const float* b_pre  = (const float*)d_in[2];
    const float* emb_W  = (const float*)d_in[3];
    const float* emb_b  = (const float*)d_in[4];
    const float* op_W   = (const float*)d_in[5];
    const float* op_b   = (const float*)d_in[6];
    const float* fc_W   = (const float*)d_in[7];
    const float* fc_b   = (const float*)d_in[8];
    const float* gnn_W  = (const float*)d_in[9];
    const float* gnn_b  = (const float*)d_in[10];
    const float* out_W  = (const float*)d_in[11];
    const float* out_b  = (const float*)d_in[12];
    const int* src         = (const int*)d_in[13];
    const int* dst         = (const int*)d_in[14];
    const int* node_assign = (const int*)d_in[15];
    float* out = (float*)d_out;

    // workspace layout (~38 MB)
    ushortT* hb  = (ushortT*)d_ws;                     // C0*HID bf16
    ushortT* htb = hb + (size_t)C0 * HID;              // NN*HID bf16
    uint2* ebuf = (uint2*)(htb + (size_t)NN * HID);    // EE uint2 (8B-aligned)
    ushortT* WT = (ushortT*)(ebuf + EE);               // 64*512 bf16
    int* ssrc   = (int*)(WT + (size_t)HID * DIN);      // EE
    int* offs   = ssrc + EE;                           // NN+1
    int* split  = offs + NN + 1;                       // NN
    int* perm   = split + NN;                          // NN
    int* nbc    = perm + NN;                           // NBC
    int* gbase  = nbc + NBC;                           // NBC
    int* koff   = gbase + NBC;                         // KK+1
    int* tmap_b = koff + KK + 1;                       // MAXT
    int* tmap_s = tmap_b + MAXT;                       // MAXT
    int* bcnt   = tmap_s + MAXT;                       // NB
    int* bbase  = bcnt + NB;                           // NB
    int* bcur   = bbase + NB;                          // NB

    hipMemsetAsync(bcnt, 0, NB * sizeof(int), stream);

    setup_k<<<GR1 + NB + 16, 256, 0, stream>>>(dst, node_assign, W_pre, bcnt, nbc, WT);
    pre_mfma<<<C0 / 64, 256, 0, stream>>>(feats0, WT, b_pre, hb);
    scan_k<<<2, 256, 0, stream>>>(bcnt, bbase, bcur, offs, nbc, gbase, koff, tmap_b, tmap_s);
    scatter_k<<<GR1 + NB, 256, 0, stream>>>(src, dst, bcur, ebuf, node_assign, gbase, perm);
    fine_scatter<<<NB, 256, 0, stream>>>(ebuf, bbase, bcur, offs, split, ssrc);
    op_fused<<<MAXT, 256, 0, stream>>>(hb, offs, split, ssrc, perm, koff, tmap_b, tmap_s,
                                       op_W, op_b, emb_W, emb_b, htb);
    fc_gemm<<<2 * FCT, 256, 0, stream>>>(htb, fc_W, fc_b);
    spmm_gnn<<<GNT, 256, 0, stream>>>(htb, offs, ssrc, gnn_W, gnn_b, out_W, out_b, out);
}

// Round 8
// 242.457 us; speedup vs baseline: 1.1187x; 1.1187x over previous
//
#include <hip/hip_runtime.h>
#include <hip/hip_bf16.h>

#define NN   100000
#define C0   40000
#define C1   30000
#define C2   30000
#define HID  64
#define KK   8
#define EE   1600000
#define DIN  512
#define NCLS 16
#define NB   196      // coarse dst buckets == node chunks (512 each)
#define BKE  2048     // edges per block in coarse pass
#define GR1  782      // ceil(EE/BKE)
#define NBC  1568     // KK*NB node-bucket counts
#define MAXT 1571     // upper bound on op-GEMM tiles
#define FCT  469      // ceil(30000/64) fc tiles per segment
#define GNT  1563     // ceil(100000/64) gnn tiles
#define AP   88       // LDS row pitch (bf16 units) for pre_mfma

typedef unsigned short ushortT;
typedef __attribute__((ext_vector_type(8))) short bf16x8;
typedef __attribute__((ext_vector_type(4))) float f32x4;

__device__ __forceinline__ float b2f(ushortT u) {
    return __uint_as_float((unsigned)u << 16);
}
__device__ __forceinline__ ushortT f2b(float x) {
    unsigned v = __float_as_uint(x);
    unsigned r = (v + 0x7FFF + ((v >> 16) & 1)) >> 16;   // RNE
    return (ushortT)r;
}
__device__ __forceinline__ unsigned pk2(float lo, float hi) {
    return (unsigned)f2b(lo) | ((unsigned)f2b(hi) << 16);
}

// ================ K1: bucket_count + nb_count + wt_conv (merged) ================
__global__ __launch_bounds__(256) void setup_k(const int* __restrict__ dst,
                                               const int* __restrict__ na,
                                               const float* __restrict__ W,
                                               int* __restrict__ bcnt,
                                               int* __restrict__ nbc,
                                               ushortT* __restrict__ WT) {
    __shared__ int sh[NB];
    const int t = threadIdx.x, b = blockIdx.x;
    if (b < GR1) {
        for (int i = t; i < NB; i += 256) sh[i] = 0;
        __syncthreads();
        const int base = b * BKE;
        for (int u = 0; u < BKE / 256; ++u) {
            int e = base + t + u * 256;
            if (e < EE) atomicAdd(&sh[dst[e] >> 9], 1);
        }
        __syncthreads();
        for (int i = t; i < NB; i += 256) {
            int c = sh[i];
            if (c) atomicAdd(&bcnt[i], c);
        }
    } else if (b < GR1 + NB) {
        const int nb_ = b - GR1;
        if (t < KK) sh[t] = 0;
        __syncthreads();
        #pragma unroll
        for (int u = 0; u < 2; ++u) {
            int n = nb_ * 512 + t + u * 256;
            if (n < NN) atomicAdd(&sh[na[n]], 1);
        }
        __syncthreads();
        if (t < KK) nbc[t * NB + nb_] = sh[t];
    } else {
        int idx = (b - GR1 - NB) * 256 + t;   // 0..4095
        int c = idx >> 6, k8 = (idx & 63) * 8;
        uint4 v;
        v.x = pk2(W[(size_t)(k8 + 0) * HID + c], W[(size_t)(k8 + 1) * HID + c]);
        v.y = pk2(W[(size_t)(k8 + 2) * HID + c], W[(size_t)(k8 + 3) * HID + c]);
        v.z = pk2(W[(size_t)(k8 + 4) * HID + c], W[(size_t)(k8 + 5) * HID + c]);
        v.w = pk2(W[(size_t)(k8 + 6) * HID + c], W[(size_t)(k8 + 7) * HID + c]);
        *(uint4*)(WT + (size_t)c * DIN + k8) = v;
    }
}

// ================ pre GEMM via MFMA ================
__global__ __launch_bounds__(256) void pre_mfma(const float* __restrict__ A,
                                                const ushortT* __restrict__ WT,
                                                const float* __restrict__ b,
                                                ushortT* __restrict__ hb) {
    __shared__ ushortT Ak[2][64 * AP];
    __shared__ ushortT Bk[2][64 * AP];
    const int tid = threadIdx.x;
    const int row0 = blockIdx.x * 64;
    const int rr = tid >> 2, q = tid & 3;
    const int w = tid >> 6, l = tid & 63;
    const int lr = l & 15, g = l >> 4;
    f32x4 acc[4] = {{0.f,0.f,0.f,0.f},{0.f,0.f,0.f,0.f},{0.f,0.f,0.f,0.f},{0.f,0.f,0.f,0.f}};
    float4 av0, av1, av2, av3;
    uint4 bv0, bv1;
    {
        const float* ap = A + (size_t)(row0 + rr) * DIN + q * 16;
        av0 = *(const float4*)(ap + 0);  av1 = *(const float4*)(ap + 4);
        av2 = *(const float4*)(ap + 8);  av3 = *(const float4*)(ap + 12);
        const uint4* bp = (const uint4*)(WT + (size_t)rr * DIN + q * 16);
        bv0 = bp[0]; bv1 = bp[1];
    }
    {
        uint4 ua0, ua1;
        ua0.x = pk2(av0.x, av0.y); ua0.y = pk2(av0.z, av0.w);
        ua0.z = pk2(av1.x, av1.y); ua0.w = pk2(av1.z, av1.w);
        ua1.x = pk2(av2.x, av2.y); ua1.y = pk2(av2.z, av2.w);
        ua1.z = pk2(av3.x, av3.y); ua1.w = pk2(av3.z, av3.w);
        *(uint4*)&Ak[0][rr * AP + q * 16] = ua0;
        *(uint4*)&Ak[0][rr * AP + q * 16 + 8] = ua1;
        *(uint4*)&Bk[0][rr * AP + q * 16] = bv0;
        *(uint4*)&Bk[0][rr * AP + q * 16 + 8] = bv1;
    }
    __syncthreads();
    for (int t = 0; t < 8; ++t) {
        if (t < 7) {
            const int k0 = (t + 1) * 64;
            const float* ap = A + (size_t)(row0 + rr) * DIN + k0 + q * 16;
            av0 = *(const float4*)(ap + 0);  av1 = *(const float4*)(ap + 4);
            av2 = *(const float4*)(ap + 8);  av3 = *(const float4*)(ap + 12);
            const uint4* bp = (const uint4*)(WT + (size_t)rr * DIN + k0 + q * 16);
            bv0 = bp[0]; bv1 = bp[1];
        }
        const int bu = t & 1;
        #pragma unroll
        for (int s = 0; s < 2; ++s) {
            bf16x8 af = *(const bf16x8*)&Ak[bu][(w * 16 + lr) * AP + s * 32 + g * 8];
            #pragma unroll
            for (int n = 0; n < 4; ++n) {
                bf16x8 bf = *(const bf16x8*)&Bk[bu][(n * 16 + lr) * AP + s * 32 + g * 8];
                acc[n] = __builtin_amdgcn_mfma_f32_16x16x32_bf16(af, bf, acc[n], 0, 0, 0);
            }
        }
        if (t < 7) {
            const int nb = (t + 1) & 1;
            uint4 ua0, ua1;
            ua0.x = pk2(av0.x, av0.y); ua0.y = pk2(av0.z, av0.w);
            ua0.z = pk2(av1.x, av1.y); ua0.w = pk2(av1.z, av1.w);
            ua1.x = pk2(av2.x, av2.y); ua1.y = pk2(av2.z, av2.w);
            ua1.z = pk2(av3.x, av3.y); ua1.w = pk2(av3.z, av3.w);
            *(uint4*)&Ak[nb][rr * AP + q * 16] = ua0;
            *(uint4*)&Ak[nb][rr * AP + q * 16 + 8] = ua1;
            *(uint4*)&Bk[nb][rr * AP + q * 16] = bv0;
            *(uint4*)&Bk[nb][rr * AP + q * 16 + 8] = bv1;
        }
        __syncthreads();
    }
    #pragma unroll
    for (int n = 0; n < 4; ++n) {
        float bb = b[n * 16 + lr];
        #pragma unroll
        for (int i = 0; i < 4; ++i) {
            int row = row0 + w * 16 + g * 4 + i;
            hb[(size_t)row * HID + n * 16 + lr] = f2b(acc[n][i] + bb);
        }
    }
}

// ================ K3: bucket_scan + nb_scan (merged) ================
__global__ __launch_bounds__(256) void scan_k(const int* __restrict__ bcnt,
                                              int* __restrict__ bbase,
                                              int* __restrict__ bcur,
                                              int* __restrict__ offs,
                                              const int* __restrict__ nbc,
                                              int* __restrict__ gbase,
                                              int* __restrict__ koff,
                                              int* __restrict__ tmap_b,
                                              int* __restrict__ tmap_s) {
    const int t = threadIdx.x;
    if (blockIdx.x == 0) {
        if (t == 0) {
            int run = 0;
            for (int i = 0; i < NB; ++i) { bbase[i] = run; bcur[i] = run; run += bcnt[i]; }
            offs[NN] = EE;
        }
        return;
    }
    __shared__ int sm[256];
    __shared__ int carry;
    __shared__ int tl[KK];
    if (t == 0) carry = 0;
    for (int i = t; i < MAXT; i += 256) tmap_b[i] = -1;
    __syncthreads();
    for (int c = 0; c < 7; ++c) {
        int i = c * 256 + t;
        int v = (i < NBC) ? nbc[i] : 0;
        sm[t] = v;
        __syncthreads();
        for (int off = 1; off < 256; off <<= 1) {
            int y = (t >= off) ? sm[t - off] : 0;
            __syncthreads();
            sm[t] += y;
            __syncthreads();
        }
        int base = carry;
        int excl = base + sm[t] - v;
        if (i < NBC) {
            gbase[i] = excl;
            if ((i % NB) == 0) koff[i / NB] = excl;
        }
        __syncthreads();
        if (t == 255) carry = base + sm[255];
        __syncthreads();
    }
    if (t == 0) {
        koff[KK] = NN;
        int run = 0;
        for (int k = 0; k < KK; ++k) {
            tl[k] = run;
            int cnt = ((k == KK - 1) ? NN : koff[k + 1]) - koff[k];
            run += (cnt + 63) / 64;
        }
    }
    __syncthreads();
    if (t < KK) {
        int k = t;
        int kb = koff[k];
        int ke = (k == KK - 1) ? NN : koff[k + 1];
        int nt = (ke - kb + 63) / 64;
        for (int tt = 0; tt < nt; ++tt) {
            tmap_b[tl[k] + tt] = k;
            tmap_s[tl[k] + tt] = kb + tt * 64;
        }
    }
}

// ================ K4: coarse_scatter + nb_scatter (merged) ================
__global__ __launch_bounds__(256) void scatter_k(const int* __restrict__ src,
                                                 const int* __restrict__ dst,
                                                 int* __restrict__ bcur,
                                                 uint2* __restrict__ ebuf,
                                                 const int* __restrict__ na,
                                                 const int* __restrict__ gbase,
                                                 int* __restrict__ perm) {
    __shared__ int s1[NB];
    __shared__ int s2[NB];
    const int t = threadIdx.x, b = blockIdx.x;
    if (b < GR1) {
        for (int i = t; i < NB; i += 256) s1[i] = 0;
        __syncthreads();
        const int base = b * BKE;
        int mys[8], myd[8], mybin[8], myrank[8];
        #pragma unroll
        for (int u = 0; u < 8; ++u) {
            int e = base + t + u * 256;
            if (e < EE) {
                int d = dst[e];
                mys[u] = src[e]; myd[u] = d; mybin[u] = d >> 9;
                myrank[u] = atomicAdd(&s1[mybin[u]], 1);
            } else mybin[u] = -1;
        }
        __syncthreads();
        for (int i = t; i < NB; i += 256) {
            int c = s1[i];
            s2[i] = c ? atomicAdd(&bcur[i], c) : 0;
        }
        __syncthreads();
        #pragma unroll
        for (int u = 0; u < 8; ++u) {
            if (mybin[u] >= 0) {
                uint2 e; e.x = (unsigned)mys[u]; e.y = (unsigned)myd[u];
                ebuf[s2[mybin[u]] + myrank[u]] = e;
            }
        }
    } else {
        const int nb_ = b - GR1;
        if (t < KK) { s1[t] = 0; s2[t] = gbase[t * NB + nb_]; }
        __syncthreads();
        #pragma unroll
        for (int u = 0; u < 2; ++u) {
            int n = nb_ * 512 + t + u * 256;
            if (n < NN) {
                int k = na[n];
                int r = atomicAdd(&s1[k], 1);
                perm[s2[k] + r] = n;
            }
        }
    }
}

// ================ r2: per-bucket exact CSR ================
__global__ __launch_bounds__(256) void fine_scatter(const uint2* __restrict__ ebuf,
                                                    const int* __restrict__ bbase,
                                                    const int* __restrict__ bend,
                                                    int* __restrict__ offs,
                                                    int* __restrict__ split,
                                                    int* __restrict__ ssrc) {
    __shared__ int hist[1024];
    __shared__ int lofs[1024];
    __shared__ int sm[256];
    const int t = threadIdx.x, b = blockIdx.x;
    const int beg = bbase[b], end = bend[b];
    for (int i = t; i < 1024; i += 256) hist[i] = 0;
    __syncthreads();
    for (int j = beg + t; j < end; j += 256) {
        uint2 e = ebuf[j];
        int bin = ((e.y & 511) << 1) | (e.x < C0 ? 0 : 1);
        atomicAdd(&hist[bin], 1);
    }
    __syncthreads();
    int v0 = hist[4 * t], v1 = hist[4 * t + 1], v2 = hist[4 * t + 2], v3 = hist[4 * t + 3];
    int ts = v0 + v1 + v2 + v3;
    sm[t] = ts;
    __syncthreads();
    for (int off = 1; off < 256; off <<= 1) {
        int y = (t >= off) ? sm[t - off] : 0;
        __syncthreads();
        sm[t] += y;
        __syncthreads();
    }
    int pre = sm[t] - ts;
    lofs[4 * t] = pre; lofs[4 * t + 1] = pre + v0;
    lofs[4 * t + 2] = pre + v0 + v1; lofs[4 * t + 3] = pre + v0 + v1 + v2;
    __syncthreads();
    const int d0 = b * 512;
    for (int i = t; i < 512; i += 256) {
        int n = d0 + i;
        if (n < NN) {
            offs[n]  = beg + lofs[2 * i];
            split[n] = beg + lofs[2 * i + 1];
        }
    }
    __syncthreads();
    for (int j = beg + t; j < end; j += 256) {
        uint2 e = ebuf[j];
        int bin = ((e.y & 511) << 1) | (e.x < C0 ? 0 : 1);
        int pos = beg + atomicAdd(&lofs[bin], 1);
        ssrc[pos] = (int)e.x;
    }
}

// ================ shared 64x64x64 GEMM core ================
__device__ __forceinline__ void gemm64(const float As[64][65], const float Bs[64][64],
                                       float acc[4][4], int tx, int ty) {
    for (int kk = 0; kk < 64; ++kk) {
        float a0 = As[ty * 4 + 0][kk], a1 = As[ty * 4 + 1][kk];
        float a2 = As[ty * 4 + 2][kk], a3 = As[ty * 4 + 3][kk];
        float4 bv = *(const float4*)(&Bs[kk][tx * 4]);
        acc[0][0] += a0 * bv.x; acc[0][1] += a0 * bv.y; acc[0][2] += a0 * bv.z; acc[0][3] += a0 * bv.w;
        acc[1][0] += a1 * bv.x; acc[1][1] += a1 * bv.y; acc[1][2] += a1 * bv.z; acc[1][3] += a1 * bv.w;
        acc[2][0] += a2 * bv.x; acc[2][1] += a2 * bv.y; acc[2][2] += a2 * bv.z; acc[2][3] += a2 * bv.w;
        acc[3][0] += a3 * bv.x; acc[3][1] += a3 * bv.y; acc[3][2] += a3 * bv.z; acc[3][3] += a3 * bv.w;
    }
}

// gather one node's row-sum into float4 (valid in sub==0 lanes after shfl reduce)
__device__ __forceinline__ float4 gather32(const ushortT* __restrict__ rows,
                                           const int* __restrict__ ssrc,
                                           int beg, int ge, int sub, int c4) {
    float4 a0 = {0.f,0.f,0.f,0.f}, a1 = {0.f,0.f,0.f,0.f};
    int j = beg + sub;
    for (; j + 2 < ge; j += 4) {
        int s0 = ssrc[j], s1 = ssrc[j + 2];
        ushort4 u = *(const ushort4*)(rows + (size_t)s0 * HID + c4 * 4);
        ushort4 v = *(const ushort4*)(rows + (size_t)s1 * HID + c4 * 4);
        a0.x += b2f(u.x); a0.y += b2f(u.y); a0.z += b2f(u.z); a0.w += b2f(u.w);
        a1.x += b2f(v.x); a1.y += b2f(v.y); a1.z += b2f(v.z); a1.w += b2f(v.w);
    }
    if (j < ge) {
        ushort4 u = *(const ushort4*)(rows + (size_t)ssrc[j] * HID + c4 * 4);
        a0.x += b2f(u.x); a0.y += b2f(u.y); a0.z += b2f(u.z); a0.w += b2f(u.w);
    }
    a0.x += a1.x; a0.y += a1.y; a0.z += a1.z; a0.w += a1.w;
    a0.x += __shfl_down(a0.x, 16); a0.y += __shfl_down(a0.y, 16);
    a0.z += __shfl_down(a0.z, 16); a0.w += __shfl_down(a0.w, 16);
    return a0;
}

// ================ op_fused: gather(filtered) + k-GEMM + skip/emb epilogue ================
__global__ __launch_bounds__(256) void op_fused(const ushortT* __restrict__ hb,
                                                const int* __restrict__ offs,
                                                const int* __restrict__ split,
                                                const int* __restrict__ ssrc,
                                                const int* __restrict__ perm,
                                                const int* __restrict__ koff,
                                                const int* __restrict__ tmap_b,
                                                const int* __restrict__ tmap_s,
                                                const float* __restrict__ op_W,
                                                const float* __restrict__ op_b,
                                                const float* __restrict__ emb_W,
                                                const float* __restrict__ emb_b,
                                                ushortT* __restrict__ htb) {
    __shared__ float As[64][65];
    __shared__ float Bs[64][64];
    __shared__ int idx[64];
    const int bk = tmap_b[blockIdx.x];
    if (bk < 0) return;
    const int start = tmap_s[blockIdx.x];
    const int kend = koff[bk + 1];
    const int tid = threadIdx.x;
    if (tid < 64) {
        int p = start + tid;
        idx[tid] = (p < kend) ? perm[p] : -1;
    }
    for (int i = tid; i < 64 * 16; i += 256) {
        int r = i >> 4, c4 = i & 15;
        *(float4*)(&Bs[r][c4 * 4]) = *(const float4*)(op_W + (size_t)bk * HID * HID + (size_t)r * HID + c4 * 4);
    }
    __syncthreads();
    const int nl0 = tid >> 5, sub = (tid >> 4) & 1, gc4 = tid & 15;
    for (int p = 0; p < 8; ++p) {
        const int nl = p * 8 + nl0;
        const int n = idx[nl];
        float4 r = {0.f, 0.f, 0.f, 0.f};
        float inv = 0.f;
        if (n >= 0) {
            const int beg = offs[n], sp = split[n], endf = offs[n + 1];
            r = gather32(hb, ssrc, beg, sp, sub, gc4);
            inv = 1.0f / fmaxf((float)(endf - beg), 1.0f);
        } else {
            r.x += __shfl_down(r.x, 16);
        }
        if (sub == 0) {
            r.x *= inv; r.y *= inv; r.z *= inv; r.w *= inv;
            *(float4*)(&As[nl][gc4 * 4]) = r;
        }
    }
    __syncthreads();
    const int tx = tid & 15, ty = tid >> 4;
    float acc[4][4] = {};
    gemm64(As, Bs, acc, tx, ty);
    float4 ob = *(const float4*)(op_b + (size_t)bk * HID + tx * 4);
    #pragma unroll
    for (int rr = 0; rr < 4; ++rr) {
        int n = idx[ty * 4 + rr];
        if (n < 0) continue;
        float4 v;
        v.x = acc[rr][0] + ob.x; v.y = acc[rr][1] + ob.y;
        v.z = acc[rr][2] + ob.z; v.w = acc[rr][3] + ob.w;
        if (n < C0) {
            ushort4 hu = *(const ushort4*)(hb + (size_t)n * HID + tx * 4);
            v.x += b2f(hu.x); v.y += b2f(hu.y); v.z += b2f(hu.z); v.w += b2f(hu.w);
        } else {
            int si = (n < C0 + C1) ? 0 : 1;
            int rn = n - C0 - si * C1;
            float4 ew = *(const float4*)(emb_W + ((size_t)si * C1 + rn) * HID + tx * 4);
            float4 eb = *(const float4*)(emb_b + (size_t)si * HID + tx * 4);
            v.x += ew.x + eb.x; v.y += ew.y + eb.y;
            v.z += ew.z + eb.z; v.w += ew.w + eb.w;
        }
        ushort4 o;
        o.x = f2b(v.x); o.y = f2b(v.y); o.z = f2b(v.z); o.w = f2b(v.w);
        *(ushort4*)(htb + (size_t)n * HID + tx * 4) = o;
    }
}

// ================ fc GEMM: contiguous segment rows, in-place htb ================
__global__ __launch_bounds__(256) void fc_gemm(ushortT* __restrict__ htb,
                                               const float* __restrict__ fc_W,
                                               const float* __restrict__ fc_b) {
    __shared__ float As[64][65];
    __shared__ float Bs[64][64];
    const int si = (blockIdx.x < FCT) ? 0 : 1;
    const int t0 = blockIdx.x - si * FCT;
    const int row0 = C0 + si * C1 + t0 * 64;
    const int lim = C0 + (si + 1) * C1;
    const int tid = threadIdx.x;
    for (int i = tid; i < 64 * 16; i += 256) {
        int r = i >> 4, c4 = i & 15;
        int n = row0 + r;
        if (n < lim) {
            ushort4 u = *(const ushort4*)(htb + (size_t)n * HID + c4 * 4);
            As[r][c4 * 4 + 0] = b2f(u.x); As[r][c4 * 4 + 1] = b2f(u.y);
            As[r][c4 * 4 + 2] = b2f(u.z); As[r][c4 * 4 + 3] = b2f(u.w);
        } else {
            As[r][c4 * 4 + 0] = 0.f; As[r][c4 * 4 + 1] = 0.f;
            As[r][c4 * 4 + 2] = 0.f; As[r][c4 * 4 + 3] = 0.f;
        }
    }
    for (int i = tid; i < 64 * 16; i += 256) {
        int r = i >> 4, c4 = i & 15;
        *(float4*)(&Bs[r][c4 * 4]) = *(const float4*)(fc_W + (size_t)si * HID * HID + (size_t)r * HID + c4 * 4);
    }
    __syncthreads();
    const int tx = tid & 15, ty = tid >> 4;
    float acc[4][4] = {};
    gemm64(As, Bs, acc, tx, ty);
    float4 fb = *(const float4*)(fc_b + (size_t)si * HID + tx * 4);
    #pragma unroll
    for (int rr = 0; rr < 4; ++rr) {
        int n = row0 + ty * 4 + rr;
        if (n >= lim) continue;
        ushort4 o;
        o.x = f2b(acc[rr][0] + fb.x); o.y = f2b(acc[rr][1] + fb.y);
        o.z = f2b(acc[rr][2] + fb.z); o.w = f2b(acc[rr][3] + fb.w);
        *(ushort4*)(htb + (size_t)n * HID + tx * 4) = o;
    }
}

// ================ spmm2: standalone, 16 lanes/node, 4-deep ILP, bf16 out ================
__global__ __launch_bounds__(256) void spmm(const ushortT* __restrict__ rows,
                                            const int* __restrict__ offs,
                                            const int* __restrict__ ssrc,
                                            ushortT* __restrict__ aggb) {
    const int t = threadIdx.x;
    const int g = t >> 4, c4 = t & 15;
    const int n = blockIdx.x * 16 + g;
    const int beg = offs[n], endf = offs[n + 1];
    float4 a0 = {0.f,0.f,0.f,0.f}, a1 = {0.f,0.f,0.f,0.f};
    float4 a2 = {0.f,0.f,0.f,0.f}, a3 = {0.f,0.f,0.f,0.f};
    int j = beg;
    for (; j + 4 <= endf; j += 4) {
        int s0 = ssrc[j], s1 = ssrc[j + 1], s2 = ssrc[j + 2], s3 = ssrc[j + 3];
        ushort4 u0 = *(const ushort4*)(rows + (size_t)s0 * HID + c4 * 4);
        ushort4 u1 = *(const ushort4*)(rows + (size_t)s1 * HID + c4 * 4);
        ushort4 u2 = *(const ushort4*)(rows + (size_t)s2 * HID + c4 * 4);
        ushort4 u3 = *(const ushort4*)(rows + (size_t)s3 * HID + c4 * 4);
        a0.x += b2f(u0.x); a0.y += b2f(u0.y); a0.z += b2f(u0.z); a0.w += b2f(u0.w);
        a1.x += b2f(u1.x); a1.y += b2f(u1.y); a1.z += b2f(u1.z); a1.w += b2f(u1.w);
        a2.x += b2f(u2.x); a2.y += b2f(u2.y); a2.z += b2f(u2.z); a2.w += b2f(u2.w);
        a3.x += b2f(u3.x); a3.y += b2f(u3.y); a3.z += b2f(u3.z); a3.w += b2f(u3.w);
    }
    for (; j < endf; ++j) {
        ushort4 u = *(const ushort4*)(rows + (size_t)ssrc[j] * HID + c4 * 4);
        a0.x += b2f(u.x); a0.y += b2f(u.y); a0.z += b2f(u.z); a0.w += b2f(u.w);
    }
    const float inv = 1.0f / fmaxf((float)(endf - beg), 1.0f);
    float4 r;
    r.x = ((a0.x + a1.x) + (a2.x + a3.x)) * inv;
    r.y = ((a0.y + a1.y) + (a2.y + a3.y)) * inv;
    r.z = ((a0.z + a1.z) + (a2.z + a3.z)) * inv;
    r.w = ((a0.w + a1.w) + (a2.w + a3.w)) * inv;
    ushort4 o;
    o.x = f2b(r.x); o.y = f2b(r.y); o.z = f2b(r.z); o.w = f2b(r.w);
    *(ushort4*)(aggb + (size_t)n * HID + c4 * 4) = o;
}

// ================ gnn GEMM + elu + logits (reads bf16 agg) ================
__global__ __launch_bounds__(256) void gnn_logits(const ushortT* __restrict__ aggb,
                                                  const float* __restrict__ gnn_W,
                                                  const float* __restrict__ gnn_b,
                                                  const float* __restrict__ out_W,
                                                  const float* __restrict__ out_b,
                                                  float* __restrict__ out) {
    __shared__ float As[64][65];
    __shared__ float Bs[64][64];
    __shared__ float Wo[64 * NCLS];
    const int row0 = blockIdx.x * 64;
    const int tid = threadIdx.x;
    for (int i = tid; i < 64 * 16; i += 256) {
        int r = i >> 4, c4 = i & 15;
        int n = row0 + r;
        if (n < NN) {
            ushort4 u = *(const ushort4*)(aggb + (size_t)n * HID + c4 * 4);
            As[r][c4 * 4 + 0] = b2f(u.x); As[r][c4 * 4 + 1] = b2f(u.y);
            As[r][c4 * 4 + 2] = b2f(u.z); As[r][c4 * 4 + 3] = b2f(u.w);
        } else {
            As[r][c4 * 4 + 0] = 0.f; As[r][c4 * 4 + 1] = 0.f;
            As[r][c4 * 4 + 2] = 0.f; As[r][c4 * 4 + 3] = 0.f;
        }
    }
    for (int i = tid; i < 64 * 16; i += 256) {
        int r = i >> 4, c4 = i & 15;
        *(float4*)(&Bs[r][c4 * 4]) = *(const float4*)(gnn_W + (size_t)r * HID + c4 * 4);
    }
    *(float4*)(&Wo[tid * 4]) = *(const float4*)(out_W + tid * 4);
    __syncthreads();
    const int tx = tid & 15, ty = tid >> 4;
    float acc[4][4] = {};
    gemm64(As, Bs, acc, tx, ty);
    __syncthreads();     // done reading As; reuse for emb
    float4 gb = *(const float4*)(gnn_b + tx * 4);
    #pragma unroll
    for (int rr = 0; rr < 4; ++rr) {
        int n = row0 + ty * 4 + rr;
        float4 v;
        v.x = acc[rr][0] + gb.x; v.y = acc[rr][1] + gb.y;
        v.z = acc[rr][2] + gb.z; v.w = acc[rr][3] + gb.w;
        v.x = (v.x > 0.f) ? v.x : expm1f(v.x);
        v.y = (v.y > 0.f) ? v.y : expm1f(v.y);
        v.z = (v.z > 0.f) ? v.z : expm1f(v.z);
        v.w = (v.w > 0.f) ? v.w : expm1f(v.w);
        As[ty * 4 + rr][tx * 4 + 0] = v.x; As[ty * 4 + rr][tx * 4 + 1] = v.y;
        As[ty * 4 + rr][tx * 4 + 2] = v.z; As[ty * 4 + rr][tx * 4 + 3] = v.w;
        if (n < NN) *(float4*)(out + (size_t)n * HID + tx * 4) = v;
    }
    __syncthreads();
    const int r = tid >> 2, cq = (tid & 3) * 4;
    float l0 = 0.f, l1 = 0.f, l2 = 0.f, l3 = 0.f;
    #pragma unroll 8
    for (int j = 0; j < 64; ++j) {
        float e = As[r][j];
        float4 w = *(const float4*)(&Wo[j * NCLS + cq]);
        l0 += e * w.x; l1 += e * w.y; l2 += e * w.z; l3 += e * w.w;
    }
    int n = row0 + r;
    if (n < NN) {
        float4 ob = *(const float4*)(out_b + cq);
        float4 lg;
        lg.x = l0 + ob.x; lg.y = l1 + ob.y; lg.z = l2 + ob.z; lg.w = l3 + ob.w;
        const size_t lbase = (size_t)NN * HID;
        *(float4*)(out + lbase + (size_t)n * NCLS + cq) = lg;
        *(float4*)(out + lbase + (size_t)NN * NCLS + (size_t)n * NCLS + cq) = lg;
    }
}

extern "C" void kernel_launch(void* const* d_in, const int* in_sizes, int n_in,
                              void* d_out, int out_size, void* d_ws, size_t ws_size,
                              hipStream_t stream) {
    const float* feats0 = (const float*)d_in[0];
    const float* W_pre  = (const float*)d_in[1];
    const float* b_pre  = (const float*)d_in[2];
    const float* emb_W  = (const float*)d_in[3];
    const float* emb_b  = (const float*)d_in[4];
    const float* op_W   = (const float*)d_in[5];
    const float* op_b   = (const float*)d_in[6];
    const float* fc_W   = (const float*)d_in[7];
    const float* fc_b   = (const float*)d_in[8];
    const float* gnn_W  = (const float*)d_in[9];
    const float* gnn_b  = (const float*)d_in[10];
    const float* out_W  = (const float*)d_in[11];
    const float* out_b  = (const float*)d_in[12];
    const int* src         = (const int*)d_in[13];
    const int* dst         = (const int*)d_in[14];
    const int* node_assign = (const int*)d_in[15];
    float* out = (float*)d_out;

    // workspace layout (~38 MB). aggb aliases ebuf (ebuf dead after fine_scatter).
    ushortT* hb  = (ushortT*)d_ws;                     // C0*HID bf16
    ushortT* htb = hb + (size_t)C0 * HID;              // NN*HID bf16
    uint2* ebuf = (uint2*)(htb + (size_t)NN * HID);    // EE uint2 (12.8 MB)
    ushortT* aggb = (ushortT*)ebuf;                    // NN*HID bf16 (12.8 MB, alias)
    ushortT* WT = (ushortT*)(ebuf + EE);               // 64*512 bf16
    int* ssrc   = (int*)(WT + (size_t)HID * DIN);      // EE
    int* offs   = ssrc + EE;                           // NN+1
    int* split  = offs + NN + 1;                       // NN
    int* perm   = split + NN;                          // NN
    int* nbc    = perm + NN;                           // NBC
    int* gbase  = nbc + NBC;                           // NBC
    int* koff   = gbase + NBC;                         // KK+1
    int* tmap_b = koff + KK + 1;                       // MAXT
    int* tmap_s = tmap_b + MAXT;                       // MAXT
    int* bcnt   = tmap_s + MAXT;                       // NB
    int* bbase  = bcnt + NB;                           // NB
    int* bcur   = bbase + NB;                          // NB

    hipMemsetAsync(bcnt, 0, NB * sizeof(int), stream);

    setup_k<<<GR1 + NB + 16, 256, 0, stream>>>(dst, node_assign, W_pre, bcnt, nbc, WT);
    pre_mfma<<<C0 / 64, 256, 0, stream>>>(feats0, WT, b_pre, hb);
    scan_k<<<2, 256, 0, stream>>>(bcnt, bbase, bcur, offs, nbc, gbase, koff, tmap_b, tmap_s);
    scatter_k<<<GR1 + NB, 256, 0, stream>>>(src, dst, bcur, ebuf, node_assign, gbase, perm);
    fine_scatter<<<NB, 256, 0, stream>>>(ebuf, bbase, bcur, offs, split, ssrc);
    op_fused<<<MAXT, 256, 0, stream>>>(hb, offs, split, ssrc, perm, koff, tmap_b, tmap_s,
                                       op_W, op_b, emb_W, emb_b, htb);
    fc_gemm<<<2 * FCT, 256, 0, stream>>>(htb, fc_W, fc_b);
    spmm<<<NN / 16, 256, 0, stream>>>(htb, offs, ssrc, aggb);
    gnn_logits<<<GNT, 256, 0, stream>>>(aggb, gnn_W, gnn_b, out_W, out_b, out);
}

// Round 9
// 229.156 us; speedup vs baseline: 1.1836x; 1.0580x over previous
//
#include <hip/hip_runtime.h>
#include <hip/hip_bf16.h>

#define NN   100000
#define C0   40000
#define C1   30000
#define C2   30000
#define HID  64
#define KK   8
#define EE   1600000
#define DIN  512
#define NCLS 16
#define NB   196      // coarse dst buckets == node chunks (512 each)
#define BKE  2048     // edges per block in coarse pass
#define GR1  782      // ceil(EE/BKE)
#define NBC  1568     // KK*NB node-bucket counts
#define MAXT 1571     // upper bound on op-GEMM tiles
#define FCT  469      // ceil(30000/64) fc tiles per segment
#define GNT  1563     // ceil(100000/64) gnn tiles
#define AP   88       // LDS row pitch (bf16 units) for pre_mfma

typedef unsigned short ushortT;
typedef __attribute__((ext_vector_type(8))) short bf16x8;
typedef __attribute__((ext_vector_type(4))) float f32x4;

__device__ __forceinline__ float b2f(ushortT u) {
    return __uint_as_float((unsigned)u << 16);
}
__device__ __forceinline__ ushortT f2b(float x) {
    unsigned v = __float_as_uint(x);
    unsigned r = (v + 0x7FFF + ((v >> 16) & 1)) >> 16;   // RNE
    return (ushortT)r;
}
__device__ __forceinline__ unsigned pk2(float lo, float hi) {
    return (unsigned)f2b(lo) | ((unsigned)f2b(hi) << 16);
}

// ================ K1: bucket_count + nb_count + wt_conv (merged) ================
__global__ __launch_bounds__(256) void setup_k(const int* __restrict__ dst,
                                               const int* __restrict__ na,
                                               const float* __restrict__ W,
                                               int* __restrict__ bcnt,
                                               int* __restrict__ nbc,
                                               ushortT* __restrict__ WT) {
    __shared__ int sh[NB];
    const int t = threadIdx.x, b = blockIdx.x;
    if (b < GR1) {
        for (int i = t; i < NB; i += 256) sh[i] = 0;
        __syncthreads();
        const int base = b * BKE;
        for (int u = 0; u < BKE / 256; ++u) {
            int e = base + t + u * 256;
            if (e < EE) atomicAdd(&sh[dst[e] >> 9], 1);
        }
        __syncthreads();
        for (int i = t; i < NB; i += 256) {
            int c = sh[i];
            if (c) atomicAdd(&bcnt[i], c);
        }
    } else if (b < GR1 + NB) {
        const int nb_ = b - GR1;
        if (t < KK) sh[t] = 0;
        __syncthreads();
        #pragma unroll
        for (int u = 0; u < 2; ++u) {
            int n = nb_ * 512 + t + u * 256;
            if (n < NN) atomicAdd(&sh[na[n]], 1);
        }
        __syncthreads();
        if (t < KK) nbc[t * NB + nb_] = sh[t];
    } else {
        int idx = (b - GR1 - NB) * 256 + t;   // 0..4095
        int c = idx >> 6, k8 = (idx & 63) * 8;
        uint4 v;
        v.x = pk2(W[(size_t)(k8 + 0) * HID + c], W[(size_t)(k8 + 1) * HID + c]);
        v.y = pk2(W[(size_t)(k8 + 2) * HID + c], W[(size_t)(k8 + 3) * HID + c]);
        v.z = pk2(W[(size_t)(k8 + 4) * HID + c], W[(size_t)(k8 + 5) * HID + c]);
        v.w = pk2(W[(size_t)(k8 + 6) * HID + c], W[(size_t)(k8 + 7) * HID + c]);
        *(uint4*)(WT + (size_t)c * DIN + k8) = v;
    }
}

// ================ pre GEMM via MFMA ================
__global__ __launch_bounds__(256) void pre_mfma(const float* __restrict__ A,
                                                const ushortT* __restrict__ WT,
                                                const float* __restrict__ b,
                                                ushortT* __restrict__ hb) {
    __shared__ ushortT Ak[2][64 * AP];
    __shared__ ushortT Bk[2][64 * AP];
    const int tid = threadIdx.x;
    const int row0 = blockIdx.x * 64;
    const int rr = tid >> 2, q = tid & 3;
    const int w = tid >> 6, l = tid & 63;
    const int lr = l & 15, g = l >> 4;
    f32x4 acc[4] = {{0.f,0.f,0.f,0.f},{0.f,0.f,0.f,0.f},{0.f,0.f,0.f,0.f},{0.f,0.f,0.f,0.f}};
    float4 av0, av1, av2, av3;
    uint4 bv0, bv1;
    {
        const float* ap = A + (size_t)(row0 + rr) * DIN + q * 16;
        av0 = *(const float4*)(ap + 0);  av1 = *(const float4*)(ap + 4);
        av2 = *(const float4*)(ap + 8);  av3 = *(const float4*)(ap + 12);
        const uint4* bp = (const uint4*)(WT + (size_t)rr * DIN + q * 16);
        bv0 = bp[0]; bv1 = bp[1];
    }
    {
        uint4 ua0, ua1;
        ua0.x = pk2(av0.x, av0.y); ua0.y = pk2(av0.z, av0.w);
        ua0.z = pk2(av1.x, av1.y); ua0.w = pk2(av1.z, av1.w);
        ua1.x = pk2(av2.x, av2.y); ua1.y = pk2(av2.z, av2.w);
        ua1.z = pk2(av3.x, av3.y); ua1.w = pk2(av3.z, av3.w);
        *(uint4*)&Ak[0][rr * AP + q * 16] = ua0;
        *(uint4*)&Ak[0][rr * AP + q * 16 + 8] = ua1;
        *(uint4*)&Bk[0][rr * AP + q * 16] = bv0;
        *(uint4*)&Bk[0][rr * AP + q * 16 + 8] = bv1;
    }
    __syncthreads();
    for (int t = 0; t < 8; ++t) {
        if (t < 7) {
            const int k0 = (t + 1) * 64;
            const float* ap = A + (size_t)(row0 + rr) * DIN + k0 + q * 16;
            av0 = *(const float4*)(ap + 0);  av1 = *(const float4*)(ap + 4);
            av2 = *(const float4*)(ap + 8);  av3 = *(const float4*)(ap + 12);
            const uint4* bp = (const uint4*)(WT + (size_t)rr * DIN + k0 + q * 16);
            bv0 = bp[0]; bv1 = bp[1];
        }
        const int bu = t & 1;
        #pragma unroll
        for (int s = 0; s < 2; ++s) {
            bf16x8 af = *(const bf16x8*)&Ak[bu][(w * 16 + lr) * AP + s * 32 + g * 8];
            #pragma unroll
            for (int n = 0; n < 4; ++n) {
                bf16x8 bf = *(const bf16x8*)&Bk[bu][(n * 16 + lr) * AP + s * 32 + g * 8];
                acc[n] = __builtin_amdgcn_mfma_f32_16x16x32_bf16(af, bf, acc[n], 0, 0, 0);
            }
        }
        if (t < 7) {
            const int nb = (t + 1) & 1;
            uint4 ua0, ua1;
            ua0.x = pk2(av0.x, av0.y); ua0.y = pk2(av0.z, av0.w);
            ua0.z = pk2(av1.x, av1.y); ua0.w = pk2(av1.z, av1.w);
            ua1.x = pk2(av2.x, av2.y); ua1.y = pk2(av2.z, av2.w);
            ua1.z = pk2(av3.x, av3.y); ua1.w = pk2(av3.z, av3.w);
            *(uint4*)&Ak[nb][rr * AP + q * 16] = ua0;
            *(uint4*)&Ak[nb][rr * AP + q * 16 + 8] = ua1;
            *(uint4*)&Bk[nb][rr * AP + q * 16] = bv0;
            *(uint4*)&Bk[nb][rr * AP + q * 16 + 8] = bv1;
        }
        __syncthreads();
    }
    #pragma unroll
    for (int n = 0; n < 4; ++n) {
        float bb = b[n * 16 + lr];
        #pragma unroll
        for (int i = 0; i < 4; ++i) {
            int row = row0 + w * 16 + g * 4 + i;
            hb[(size_t)row * HID + n * 16 + lr] = f2b(acc[n][i] + bb);
        }
    }
}

// ================ K3: bucket_scan + nb_scan (merged) ================
__global__ __launch_bounds__(256) void scan_k(const int* __restrict__ bcnt,
                                              int* __restrict__ bbase,
                                              int* __restrict__ bcur,
                                              int* __restrict__ offs,
                                              const int* __restrict__ nbc,
                                              int* __restrict__ gbase,
                                              int* __restrict__ koff,
                                              int* __restrict__ tmap_b,
                                              int* __restrict__ tmap_s) {
    const int t = threadIdx.x;
    if (blockIdx.x == 0) {
        if (t == 0) {
            int run = 0;
            for (int i = 0; i < NB; ++i) { bbase[i] = run; bcur[i] = run; run += bcnt[i]; }
            offs[NN] = EE;
        }
        return;
    }
    __shared__ int sm[256];
    __shared__ int carry;
    __shared__ int tl[KK];
    if (t == 0) carry = 0;
    for (int i = t; i < MAXT; i += 256) tmap_b[i] = -1;
    __syncthreads();
    for (int c = 0; c < 7; ++c) {
        int i = c * 256 + t;
        int v = (i < NBC) ? nbc[i] : 0;
        sm[t] = v;
        __syncthreads();
        for (int off = 1; off < 256; off <<= 1) {
            int y = (t >= off) ? sm[t - off] : 0;
            __syncthreads();
            sm[t] += y;
            __syncthreads();
        }
        int base = carry;
        int excl = base + sm[t] - v;
        if (i < NBC) {
            gbase[i] = excl;
            if ((i % NB) == 0) koff[i / NB] = excl;
        }
        __syncthreads();
        if (t == 255) carry = base + sm[255];
        __syncthreads();
    }
    if (t == 0) {
        koff[KK] = NN;
        int run = 0;
        for (int k = 0; k < KK; ++k) {
            tl[k] = run;
            int cnt = ((k == KK - 1) ? NN : koff[k + 1]) - koff[k];
            run += (cnt + 63) / 64;
        }
    }
    __syncthreads();
    if (t < KK) {
        int k = t;
        int kb = koff[k];
        int ke = (k == KK - 1) ? NN : koff[k + 1];
        int nt = (ke - kb + 63) / 64;
        for (int tt = 0; tt < nt; ++tt) {
            tmap_b[tl[k] + tt] = k;
            tmap_s[tl[k] + tt] = kb + tt * 64;
        }
    }
}

// ================ K4: coarse_scatter + nb_scatter (merged) ================
__global__ __launch_bounds__(256) void scatter_k(const int* __restrict__ src,
                                                 const int* __restrict__ dst,
                                                 int* __restrict__ bcur,
                                                 uint2* __restrict__ ebuf,
                                                 const int* __restrict__ na,
                                                 const int* __restrict__ gbase,
                                                 int* __restrict__ perm) {
    __shared__ int s1[NB];
    __shared__ int s2[NB];
    const int t = threadIdx.x, b = blockIdx.x;
    if (b < GR1) {
        for (int i = t; i < NB; i += 256) s1[i] = 0;
        __syncthreads();
        const int base = b * BKE;
        int mys[8], myd[8], mybin[8], myrank[8];
        #pragma unroll
        for (int u = 0; u < 8; ++u) {
            int e = base + t + u * 256;
            if (e < EE) {
                int d = dst[e];
                mys[u] = src[e]; myd[u] = d; mybin[u] = d >> 9;
                myrank[u] = atomicAdd(&s1[mybin[u]], 1);
            } else mybin[u] = -1;
        }
        __syncthreads();
        for (int i = t; i < NB; i += 256) {
            int c = s1[i];
            s2[i] = c ? atomicAdd(&bcur[i], c) : 0;
        }
        __syncthreads();
        #pragma unroll
        for (int u = 0; u < 8; ++u) {
            if (mybin[u] >= 0) {
                uint2 e; e.x = (unsigned)mys[u]; e.y = (unsigned)myd[u];
                ebuf[s2[mybin[u]] + myrank[u]] = e;
            }
        }
    } else {
        const int nb_ = b - GR1;
        if (t < KK) { s1[t] = 0; s2[t] = gbase[t * NB + nb_]; }
        __syncthreads();
        #pragma unroll
        for (int u = 0; u < 2; ++u) {
            int n = nb_ * 512 + t + u * 256;
            if (n < NN) {
                int k = na[n];
                int r = atomicAdd(&s1[k], 1);
                perm[s2[k] + r] = n;
            }
        }
    }
}

// ================ r2: per-bucket exact CSR ================
__global__ __launch_bounds__(256) void fine_scatter(const uint2* __restrict__ ebuf,
                                                    const int* __restrict__ bbase,
                                                    const int* __restrict__ bend,
                                                    int* __restrict__ offs,
                                                    int* __restrict__ split,
                                                    int* __restrict__ ssrc) {
    __shared__ int hist[1024];
    __shared__ int lofs[1024];
    __shared__ int sm[256];
    const int t = threadIdx.x, b = blockIdx.x;
    const int beg = bbase[b], end = bend[b];
    for (int i = t; i < 1024; i += 256) hist[i] = 0;
    __syncthreads();
    for (int j = beg + t; j < end; j += 256) {
        uint2 e = ebuf[j];
        int bin = ((e.y & 511) << 1) | (e.x < C0 ? 0 : 1);
        atomicAdd(&hist[bin], 1);
    }
    __syncthreads();
    int v0 = hist[4 * t], v1 = hist[4 * t + 1], v2 = hist[4 * t + 2], v3 = hist[4 * t + 3];
    int ts = v0 + v1 + v2 + v3;
    sm[t] = ts;
    __syncthreads();
    for (int off = 1; off < 256; off <<= 1) {
        int y = (t >= off) ? sm[t - off] : 0;
        __syncthreads();
        sm[t] += y;
        __syncthreads();
    }
    int pre = sm[t] - ts;
    lofs[4 * t] = pre; lofs[4 * t + 1] = pre + v0;
    lofs[4 * t + 2] = pre + v0 + v1; lofs[4 * t + 3] = pre + v0 + v1 + v2;
    __syncthreads();
    const int d0 = b * 512;
    for (int i = t; i < 512; i += 256) {
        int n = d0 + i;
        if (n < NN) {
            offs[n]  = beg + lofs[2 * i];
            split[n] = beg + lofs[2 * i + 1];
        }
    }
    __syncthreads();
    for (int j = beg + t; j < end; j += 256) {
        uint2 e = ebuf[j];
        int bin = ((e.y & 511) << 1) | (e.x < C0 ? 0 : 1);
        int pos = beg + atomicAdd(&lofs[bin], 1);
        ssrc[pos] = (int)e.x;
    }
}

// ================ spmm: standalone, 16 lanes/node, 4-deep ILP, bf16 out ================
// splt != nullptr -> gather only [beg, splt[n]) but normalize by full degree.
__global__ __launch_bounds__(256) void spmm(const ushortT* __restrict__ rows,
                                            const int* __restrict__ offs,
                                            const int* __restrict__ splt,
                                            const int* __restrict__ ssrc,
                                            ushortT* __restrict__ aggb) {
    const int t = threadIdx.x;
    const int g = t >> 4, c4 = t & 15;
    const int n = blockIdx.x * 16 + g;
    const int beg = offs[n], endf = offs[n + 1];
    const int ge = splt ? splt[n] : endf;
    float4 a0 = {0.f,0.f,0.f,0.f}, a1 = {0.f,0.f,0.f,0.f};
    float4 a2 = {0.f,0.f,0.f,0.f}, a3 = {0.f,0.f,0.f,0.f};
    int j = beg;
    for (; j + 4 <= ge; j += 4) {
        int s0 = ssrc[j], s1 = ssrc[j + 1], s2 = ssrc[j + 2], s3 = ssrc[j + 3];
        ushort4 u0 = *(const ushort4*)(rows + (size_t)s0 * HID + c4 * 4);
        ushort4 u1 = *(const ushort4*)(rows + (size_t)s1 * HID + c4 * 4);
        ushort4 u2 = *(const ushort4*)(rows + (size_t)s2 * HID + c4 * 4);
        ushort4 u3 = *(const ushort4*)(rows + (size_t)s3 * HID + c4 * 4);
        a0.x += b2f(u0.x); a0.y += b2f(u0.y); a0.z += b2f(u0.z); a0.w += b2f(u0.w);
        a1.x += b2f(u1.x); a1.y += b2f(u1.y); a1.z += b2f(u1.z); a1.w += b2f(u1.w);
        a2.x += b2f(u2.x); a2.y += b2f(u2.y); a2.z += b2f(u2.z); a2.w += b2f(u2.w);
        a3.x += b2f(u3.x); a3.y += b2f(u3.y); a3.z += b2f(u3.z); a3.w += b2f(u3.w);
    }
    for (; j < ge; ++j) {
        ushort4 u = *(const ushort4*)(rows + (size_t)ssrc[j] * HID + c4 * 4);
        a0.x += b2f(u.x); a0.y += b2f(u.y); a0.z += b2f(u.z); a0.w += b2f(u.w);
    }
    const float inv = 1.0f / fmaxf((float)(endf - beg), 1.0f);
    float4 r;
    r.x = ((a0.x + a1.x) + (a2.x + a3.x)) * inv;
    r.y = ((a0.y + a1.y) + (a2.y + a3.y)) * inv;
    r.z = ((a0.z + a1.z) + (a2.z + a3.z)) * inv;
    r.w = ((a0.w + a1.w) + (a2.w + a3.w)) * inv;
    ushort4 o;
    o.x = f2b(r.x); o.y = f2b(r.y); o.z = f2b(r.z); o.w = f2b(r.w);
    *(ushort4*)(aggb + (size_t)n * HID + c4 * 4) = o;
}

// ================ shared 64x64x64 GEMM core ================
__device__ __forceinline__ void gemm64(const float As[64][65], const float Bs[64][64],
                                       float acc[4][4], int tx, int ty) {
    for (int kk = 0; kk < 64; ++kk) {
        float a0 = As[ty * 4 + 0][kk], a1 = As[ty * 4 + 1][kk];
        float a2 = As[ty * 4 + 2][kk], a3 = As[ty * 4 + 3][kk];
        float4 bv = *(const float4*)(&Bs[kk][tx * 4]);
        acc[0][0] += a0 * bv.x; acc[0][1] += a0 * bv.y; acc[0][2] += a0 * bv.z; acc[0][3] += a0 * bv.w;
        acc[1][0] += a1 * bv.x; acc[1][1] += a1 * bv.y; acc[1][2] += a1 * bv.z; acc[1][3] += a1 * bv.w;
        acc[2][0] += a2 * bv.x; acc[2][1] += a2 * bv.y; acc[2][2] += a2 * bv.z; acc[2][3] += a2 * bv.w;
        acc[3][0] += a3 * bv.x; acc[3][1] += a3 * bv.y; acc[3][2] += a3 * bv.z; acc[3][3] += a3 * bv.w;
    }
}

// ================ op GEMM: k-bucketed tiles, reads bf16 agg -> htb ================
__global__ __launch_bounds__(256) void op_gemm(const ushortT* __restrict__ aggb,
                                               const ushortT* __restrict__ hb,
                                               const int* __restrict__ perm,
                                               const int* __restrict__ koff,
                                               const int* __restrict__ tmap_b,
                                               const int* __restrict__ tmap_s,
                                               const float* __restrict__ op_W,
                                               const float* __restrict__ op_b,
                                               const float* __restrict__ emb_W,
                                               const float* __restrict__ emb_b,
                                               ushortT* __restrict__ htb) {
    __shared__ float As[64][65];
    __shared__ float Bs[64][64];
    __shared__ int idx[64];
    const int bk = tmap_b[blockIdx.x];
    if (bk < 0) return;
    const int start = tmap_s[blockIdx.x];
    const int kend = koff[bk + 1];
    const int tid = threadIdx.x;
    if (tid < 64) {
        int p = start + tid;
        idx[tid] = (p < kend) ? perm[p] : -1;
    }
    __syncthreads();
    for (int i = tid; i < 64 * 16; i += 256) {
        int r = i >> 4, c4 = i & 15;
        int n = idx[r];
        if (n >= 0) {
            ushort4 u = *(const ushort4*)(aggb + (size_t)n * HID + c4 * 4);
            As[r][c4 * 4 + 0] = b2f(u.x); As[r][c4 * 4 + 1] = b2f(u.y);
            As[r][c4 * 4 + 2] = b2f(u.z); As[r][c4 * 4 + 3] = b2f(u.w);
        } else {
            As[r][c4 * 4 + 0] = 0.f; As[r][c4 * 4 + 1] = 0.f;
            As[r][c4 * 4 + 2] = 0.f; As[r][c4 * 4 + 3] = 0.f;
        }
    }
    for (int i = tid; i < 64 * 16; i += 256) {
        int r = i >> 4, c4 = i & 15;
        *(float4*)(&Bs[r][c4 * 4]) = *(const float4*)(op_W + (size_t)bk * HID * HID + (size_t)r * HID + c4 * 4);
    }
    __syncthreads();
    const int tx = tid & 15, ty = tid >> 4;
    float acc[4][4] = {};
    gemm64(As, Bs, acc, tx, ty);
    float4 ob = *(const float4*)(op_b + (size_t)bk * HID + tx * 4);
    #pragma unroll
    for (int rr = 0; rr < 4; ++rr) {
        int n = idx[ty * 4 + rr];
        if (n < 0) continue;
        float4 v;
        v.x = acc[rr][0] + ob.x; v.y = acc[rr][1] + ob.y;
        v.z = acc[rr][2] + ob.z; v.w = acc[rr][3] + ob.w;
        if (n < C0) {
            ushort4 hu = *(const ushort4*)(hb + (size_t)n * HID + tx * 4);
            v.x += b2f(hu.x); v.y += b2f(hu.y); v.z += b2f(hu.z); v.w += b2f(hu.w);
        } else {
            int si = (n < C0 + C1) ? 0 : 1;
            int rn = n - C0 - si * C1;
            float4 ew = *(const float4*)(emb_W + ((size_t)si * C1 + rn) * HID + tx * 4);
            float4 eb = *(const float4*)(emb_b + (size_t)si * HID + tx * 4);
            v.x += ew.x + eb.x; v.y += ew.y + eb.y;
            v.z += ew.z + eb.z; v.w += ew.w + eb.w;
        }
        ushort4 o;
        o.x = f2b(v.x); o.y = f2b(v.y); o.z = f2b(v.z); o.w = f2b(v.w);
        *(ushort4*)(htb + (size_t)n * HID + tx * 4) = o;
    }
}

// ================ fc GEMM: contiguous segment rows, in-place htb ================
__global__ __launch_bounds__(256) void fc_gemm(ushortT* __restrict__ htb,
                                               const float* __restrict__ fc_W,
                                               const float* __restrict__ fc_b) {
    __shared__ float As[64][65];
    __shared__ float Bs[64][64];
    const int si = (blockIdx.x < FCT) ? 0 : 1;
    const int t0 = blockIdx.x - si * FCT;
    const int row0 = C0 + si * C1 + t0 * 64;
    const int lim = C0 + (si + 1) * C1;
    const int tid = threadIdx.x;
    for (int i = tid; i < 64 * 16; i += 256) {
        int r = i >> 4, c4 = i & 15;
        int n = row0 + r;
        if (n < lim) {
            ushort4 u = *(const ushort4*)(htb + (size_t)n * HID + c4 * 4);
            As[r][c4 * 4 + 0] = b2f(u.x); As[r][c4 * 4 + 1] = b2f(u.y);
            As[r][c4 * 4 + 2] = b2f(u.z); As[r][c4 * 4 + 3] = b2f(u.w);
        } else {
            As[r][c4 * 4 + 0] = 0.f; As[r][c4 * 4 + 1] = 0.f;
            As[r][c4 * 4 + 2] = 0.f; As[r][c4 * 4 + 3] = 0.f;
        }
    }
    for (int i = tid; i < 64 * 16; i += 256) {
        int r = i >> 4, c4 = i & 15;
        *(float4*)(&Bs[r][c4 * 4]) = *(const float4*)(fc_W + (size_t)si * HID * HID + (size_t)r * HID + c4 * 4);
    }
    __syncthreads();
    const int tx = tid & 15, ty = tid >> 4;
    float acc[4][4] = {};
    gemm64(As, Bs, acc, tx, ty);
    float4 fb = *(const float4*)(fc_b + (size_t)si * HID + tx * 4);
    #pragma unroll
    for (int rr = 0; rr < 4; ++rr) {
        int n = row0 + ty * 4 + rr;
        if (n >= lim) continue;
        ushort4 o;
        o.x = f2b(acc[rr][0] + fb.x); o.y = f2b(acc[rr][1] + fb.y);
        o.z = f2b(acc[rr][2] + fb.z); o.w = f2b(acc[rr][3] + fb.w);
        *(ushort4*)(htb + (size_t)n * HID + tx * 4) = o;
    }
}

// ================ gnn GEMM + elu + logits (reads bf16 agg) ================
__global__ __launch_bounds__(256) void gnn_logits(const ushortT* __restrict__ aggb,
                                                  const float* __restrict__ gnn_W,
                                                  const float* __restrict__ gnn_b,
                                                  const float* __restrict__ out_W,
                                                  const float* __restrict__ out_b,
                                                  float* __restrict__ out) {
    __shared__ float As[64][65];
    __shared__ float Bs[64][64];
    __shared__ float Wo[64 * NCLS];
    const int row0 = blockIdx.x * 64;
    const int tid = threadIdx.x;
    for (int i = tid; i < 64 * 16; i += 256) {
        int r = i >> 4, c4 = i & 15;
        int n = row0 + r;
        if (n < NN) {
            ushort4 u = *(const ushort4*)(aggb + (size_t)n * HID + c4 * 4);
            As[r][c4 * 4 + 0] = b2f(u.x); As[r][c4 * 4 + 1] = b2f(u.y);
            As[r][c4 * 4 + 2] = b2f(u.z); As[r][c4 * 4 + 3] = b2f(u.w);
        } else {
            As[r][c4 * 4 + 0] = 0.f; As[r][c4 * 4 + 1] = 0.f;
            As[r][c4 * 4 + 2] = 0.f; As[r][c4 * 4 + 3] = 0.f;
        }
    }
    for (int i = tid; i < 64 * 16; i += 256) {
        int r = i >> 4, c4 = i & 15;
        *(float4*)(&Bs[r][c4 * 4]) = *(const float4*)(gnn_W + (size_t)r * HID + c4 * 4);
    }
    *(float4*)(&Wo[tid * 4]) = *(const float4*)(out_W + tid * 4);
    __syncthreads();
    const int tx = tid & 15, ty = tid >> 4;
    float acc[4][4] = {};
    gemm64(As, Bs, acc, tx, ty);
    __syncthreads();     // done reading As; reuse for emb
    float4 gb = *(const float4*)(gnn_b + tx * 4);
    #pragma unroll
    for (int rr = 0; rr < 4; ++rr) {
        int n = row0 + ty * 4 + rr;
        float4 v;
        v.x = acc[rr][0] + gb.x; v.y = acc[rr][1] + gb.y;
        v.z = acc[rr][2] + gb.z; v.w = acc[rr][3] + gb.w;
        v.x = (v.x > 0.f) ? v.x : expm1f(v.x);
        v.y = (v.y > 0.f) ? v.y : expm1f(v.y);
        v.z = (v.z > 0.f) ? v.z : expm1f(v.z);
        v.w = (v.w > 0.f) ? v.w : expm1f(v.w);
        As[ty * 4 + rr][tx * 4 + 0] = v.x; As[ty * 4 + rr][tx * 4 + 1] = v.y;
        As[ty * 4 + rr][tx * 4 + 2] = v.z; As[ty * 4 + rr][tx * 4 + 3] = v.w;
        if (n < NN) *(float4*)(out + (size_t)n * HID + tx * 4) = v;
    }
    __syncthreads();
    const int r = tid >> 2, cq = (tid & 3) * 4;
    float l0 = 0.f, l1 = 0.f, l2 = 0.f, l3 = 0.f;
    #pragma unroll 8
    for (int j = 0; j < 64; ++j) {
        float e = As[r][j];
        float4 w = *(const float4*)(&Wo[j * NCLS + cq]);
        l0 += e * w.x; l1 += e * w.y; l2 += e * w.z; l3 += e * w.w;
    }
    int n = row0 + r;
    if (n < NN) {
        float4 ob = *(const float4*)(out_b + cq);
        float4 lg;
        lg.x = l0 + ob.x; lg.y = l1 + ob.y; lg.z = l2 + ob.z; lg.w = l3 + ob.w;
        const size_t lbase = (size_t)NN * HID;
        *(float4*)(out + lbase + (size_t)n * NCLS + cq) = lg;
        *(float4*)(out + lbase + (size_t)NN * NCLS + (size_t)n * NCLS + cq) = lg;
    }
}

extern "C" void kernel_launch(void* const* d_in, const int* in_sizes, int n_in,
                              void* d_out, int out_size, void* d_ws, size_t ws_size,
                              hipStream_t stream) {
    const float* feats0 = (const float*)d_in[0];
    const float* W_pre  = (const float*)d_in[1];
    const float* b_pre  = (const float*)d_in[2];
    const float* emb_W  = (const float*)d_in[3];
    const float* emb_b  = (const float*)d_in[4];
    const float* op_W   = (const float*)d_in[5];
    const float* op_b   = (const float*)d_in[6];
    const float* fc_W   = (const float*)d_in[7];
    const float* fc_b   = (const float*)d_in[8];
    const float* gnn_W  = (const float*)d_in[9];
    const float* gnn_b  = (const float*)d_in[10];
    const float* out_W  = (const float*)d_in[11];
    const float* out_b  = (const float*)d_in[12];
    const int* src         = (const int*)d_in[13];
    const int* dst         = (const int*)d_in[14];
    const int* node_assign = (const int*)d_in[15];
    float* out = (float*)d_out;

    // workspace layout (~38 MB). aggb aliases ebuf (ebuf dead after fine_scatter;
    // aggb written by spmm1, consumed by op_gemm, rewritten by spmm2, consumed by gnn).
    ushortT* hb  = (ushortT*)d_ws;                     // C0*HID bf16
    ushortT* htb = hb + (size_t)C0 * HID;              // NN*HID bf16
    uint2* ebuf = (uint2*)(htb + (size_t)NN * HID);    // EE uint2 (12.8 MB)
    ushortT* aggb = (ushortT*)ebuf;                    // NN*HID bf16 (12.8 MB, alias)
    ushortT* WT = (ushortT*)(ebuf + EE);               // 64*512 bf16
    int* ssrc   = (int*)(WT + (size_t)HID * DIN);      // EE
    int* offs   = ssrc + EE;                           // NN+1
    int* split  = offs + NN + 1;                       // NN
    int* perm   = split + NN;                          // NN
    int* nbc    = perm + NN;                           // NBC
    int* gbase  = nbc + NBC;                           // NBC
    int* koff   = gbase + NBC;                         // KK+1
    int* tmap_b = koff + KK + 1;                       // MAXT
    int* tmap_s = tmap_b + MAXT;                       // MAXT
    int* bcnt   = tmap_s + MAXT;                       // NB
    int* bbase  = bcnt + NB;                           // NB
    int* bcur   = bbase + NB;                          // NB

    hipMemsetAsync(bcnt, 0, NB * sizeof(int), stream);

    setup_k<<<GR1 + NB + 16, 256, 0, stream>>>(dst, node_assign, W_pre, bcnt, nbc, WT);
    pre_mfma<<<C0 / 64, 256, 0, stream>>>(feats0, WT, b_pre, hb);
    scan_k<<<2, 256, 0, stream>>>(bcnt, bbase, bcur, offs, nbc, gbase, koff, tmap_b, tmap_s);
    scatter_k<<<GR1 + NB, 256, 0, stream>>>(src, dst, bcur, ebuf, node_assign, gbase, perm);
    fine_scatter<<<NB, 256, 0, stream>>>(ebuf, bbase, bcur, offs, split, ssrc);
    spmm<<<NN / 16, 256, 0, stream>>>(hb, offs, split, ssrc, aggb);          // filtered
    op_gemm<<<MAXT, 256, 0, stream>>>(aggb, hb, perm, koff, tmap_b, tmap_s,
                                      op_W, op_b, emb_W, emb_b, htb);
    fc_gemm<<<2 * FCT, 256, 0, stream>>>(htb, fc_W, fc_b);
    spmm<<<NN / 16, 256, 0, stream>>>(htb, offs, nullptr, ssrc, aggb);       // full
    gnn_logits<<<GNT, 256, 0, stream>>>(aggb, gnn_W, gnn_b, out_W, out_b, out);
}

// Round 10
// 223.152 us; speedup vs baseline: 1.2154x; 1.0269x over previous
//
#include <hip/hip_runtime.h>
#include <hip/hip_bf16.h>

#define NN   100000
#define C0   40000
#define C1   30000
#define C2   30000
#define HID  64
#define KK   8
#define EE   1600000
#define DIN  512
#define NCLS 16
#define NB   196      // coarse dst buckets == node chunks (512 each)
#define BKE  2048     // edges per block in coarse pass
#define GR1  782      // ceil(EE/BKE)
#define NBC  1568     // KK*NB node-bucket counts
#define MAXT 1571     // upper bound on op-GEMM tiles
#define FCT  469      // ceil(30000/64) fc tiles per segment
#define GNT  1563     // ceil(100000/64) gnn tiles
#define AP   88       // LDS row pitch (bf16 units) for pre_mfma

typedef unsigned short ushortT;
typedef __attribute__((ext_vector_type(8))) short bf16x8;
typedef __attribute__((ext_vector_type(4))) float f32x4;

__device__ __forceinline__ float b2f(ushortT u) {
    return __uint_as_float((unsigned)u << 16);
}
__device__ __forceinline__ ushortT f2b(float x) {
    unsigned v = __float_as_uint(x);
    unsigned r = (v + 0x7FFF + ((v >> 16) & 1)) >> 16;   // RNE
    return (ushortT)r;
}
__device__ __forceinline__ unsigned pk2(float lo, float hi) {
    return (unsigned)f2b(lo) | ((unsigned)f2b(hi) << 16);
}
__device__ __forceinline__ void acc8f(float* a, uint4 v) {
    a[0] += b2f((ushortT)(v.x & 0xFFFF)); a[1] += b2f((ushortT)(v.x >> 16));
    a[2] += b2f((ushortT)(v.y & 0xFFFF)); a[3] += b2f((ushortT)(v.y >> 16));
    a[4] += b2f((ushortT)(v.z & 0xFFFF)); a[5] += b2f((ushortT)(v.z >> 16));
    a[6] += b2f((ushortT)(v.w & 0xFFFF)); a[7] += b2f((ushortT)(v.w >> 16));
}

// ================ K1: bucket_count + nb_count + wt_conv (merged) ================
__global__ __launch_bounds__(256) void setup_k(const int* __restrict__ dst,
                                               const int* __restrict__ na,
                                               const float* __restrict__ W,
                                               int* __restrict__ bcnt,
                                               int* __restrict__ nbc,
                                               ushortT* __restrict__ WT) {
    __shared__ int sh[NB];
    const int t = threadIdx.x, b = blockIdx.x;
    if (b < GR1) {
        for (int i = t; i < NB; i += 256) sh[i] = 0;
        __syncthreads();
        const int base = b * BKE;
        for (int u = 0; u < BKE / 256; ++u) {
            int e = base + t + u * 256;
            if (e < EE) atomicAdd(&sh[dst[e] >> 9], 1);
        }
        __syncthreads();
        for (int i = t; i < NB; i += 256) {
            int c = sh[i];
            if (c) atomicAdd(&bcnt[i], c);
        }
    } else if (b < GR1 + NB) {
        const int nb_ = b - GR1;
        if (t < KK) sh[t] = 0;
        __syncthreads();
        #pragma unroll
        for (int u = 0; u < 2; ++u) {
            int n = nb_ * 512 + t + u * 256;
            if (n < NN) atomicAdd(&sh[na[n]], 1);
        }
        __syncthreads();
        if (t < KK) nbc[t * NB + nb_] = sh[t];
    } else {
        int idx = (b - GR1 - NB) * 256 + t;   // 0..4095
        int c = idx >> 6, k8 = (idx & 63) * 8;
        uint4 v;
        v.x = pk2(W[(size_t)(k8 + 0) * HID + c], W[(size_t)(k8 + 1) * HID + c]);
        v.y = pk2(W[(size_t)(k8 + 2) * HID + c], W[(size_t)(k8 + 3) * HID + c]);
        v.z = pk2(W[(size_t)(k8 + 4) * HID + c], W[(size_t)(k8 + 5) * HID + c]);
        v.w = pk2(W[(size_t)(k8 + 6) * HID + c], W[(size_t)(k8 + 7) * HID + c]);
        *(uint4*)(WT + (size_t)c * DIN + k8) = v;
    }
}

// ================ pre GEMM via MFMA ================
__global__ __launch_bounds__(256) void pre_mfma(const float* __restrict__ A,
                                                const ushortT* __restrict__ WT,
                                                const float* __restrict__ b,
                                                ushortT* __restrict__ hb) {
    __shared__ ushortT Ak[2][64 * AP];
    __shared__ ushortT Bk[2][64 * AP];
    const int tid = threadIdx.x;
    const int row0 = blockIdx.x * 64;
    const int rr = tid >> 2, q = tid & 3;
    const int w = tid >> 6, l = tid & 63;
    const int lr = l & 15, g = l >> 4;
    f32x4 acc[4] = {{0.f,0.f,0.f,0.f},{0.f,0.f,0.f,0.f},{0.f,0.f,0.f,0.f},{0.f,0.f,0.f,0.f}};
    float4 av0, av1, av2, av3;
    uint4 bv0, bv1;
    {
        const float* ap = A + (size_t)(row0 + rr) * DIN + q * 16;
        av0 = *(const float4*)(ap + 0);  av1 = *(const float4*)(ap + 4);
        av2 = *(const float4*)(ap + 8);  av3 = *(const float4*)(ap + 12);
        const uint4* bp = (const uint4*)(WT + (size_t)rr * DIN + q * 16);
        bv0 = bp[0]; bv1 = bp[1];
    }
    {
        uint4 ua0, ua1;
        ua0.x = pk2(av0.x, av0.y); ua0.y = pk2(av0.z, av0.w);
        ua0.z = pk2(av1.x, av1.y); ua0.w = pk2(av1.z, av1.w);
        ua1.x = pk2(av2.x, av2.y); ua1.y = pk2(av2.z, av2.w);
        ua1.z = pk2(av3.x, av3.y); ua1.w = pk2(av3.z, av3.w);
        *(uint4*)&Ak[0][rr * AP + q * 16] = ua0;
        *(uint4*)&Ak[0][rr * AP + q * 16 + 8] = ua1;
        *(uint4*)&Bk[0][rr * AP + q * 16] = bv0;
        *(uint4*)&Bk[0][rr * AP + q * 16 + 8] = bv1;
    }
    __syncthreads();
    for (int t = 0; t < 8; ++t) {
        if (t < 7) {
            const int k0 = (t + 1) * 64;
            const float* ap = A + (size_t)(row0 + rr) * DIN + k0 + q * 16;
            av0 = *(const float4*)(ap + 0);  av1 = *(const float4*)(ap + 4);
            av2 = *(const float4*)(ap + 8);  av3 = *(const float4*)(ap + 12);
            const uint4* bp = (const uint4*)(WT + (size_t)rr * DIN + k0 + q * 16);
            bv0 = bp[0]; bv1 = bp[1];
        }
        const int bu = t & 1;
        #pragma unroll
        for (int s = 0; s < 2; ++s) {
            bf16x8 af = *(const bf16x8*)&Ak[bu][(w * 16 + lr) * AP + s * 32 + g * 8];
            #pragma unroll
            for (int n = 0; n < 4; ++n) {
                bf16x8 bf = *(const bf16x8*)&Bk[bu][(n * 16 + lr) * AP + s * 32 + g * 8];
                acc[n] = __builtin_amdgcn_mfma_f32_16x16x32_bf16(af, bf, acc[n], 0, 0, 0);
            }
        }
        if (t < 7) {
            const int nb = (t + 1) & 1;
            uint4 ua0, ua1;
            ua0.x = pk2(av0.x, av0.y); ua0.y = pk2(av0.z, av0.w);
            ua0.z = pk2(av1.x, av1.y); ua0.w = pk2(av1.z, av1.w);
            ua1.x = pk2(av2.x, av2.y); ua1.y = pk2(av2.z, av2.w);
            ua1.z = pk2(av3.x, av3.y); ua1.w = pk2(av3.z, av3.w);
            *(uint4*)&Ak[nb][rr * AP + q * 16] = ua0;
            *(uint4*)&Ak[nb][rr * AP + q * 16 + 8] = ua1;
            *(uint4*)&Bk[nb][rr * AP + q * 16] = bv0;
            *(uint4*)&Bk[nb][rr * AP + q * 16 + 8] = bv1;
        }
        __syncthreads();
    }
    #pragma unroll
    for (int n = 0; n < 4; ++n) {
        float bb = b[n * 16 + lr];
        #pragma unroll
        for (int i = 0; i < 4; ++i) {
            int row = row0 + w * 16 + g * 4 + i;
            hb[(size_t)row * HID + n * 16 + lr] = f2b(acc[n][i] + bb);
        }
    }
}

// ================ K3: bucket_scan + nb_scan (merged) ================
__global__ __launch_bounds__(256) void scan_k(const int* __restrict__ bcnt,
                                              int* __restrict__ bbase,
                                              int* __restrict__ bcur,
                                              int* __restrict__ offs,
                                              const int* __restrict__ nbc,
                                              int* __restrict__ gbase,
                                              int* __restrict__ koff,
                                              int* __restrict__ tmap_b,
                                              int* __restrict__ tmap_s) {
    const int t = threadIdx.x;
    if (blockIdx.x == 0) {
        if (t == 0) {
            int run = 0;
            for (int i = 0; i < NB; ++i) { bbase[i] = run; bcur[i] = run; run += bcnt[i]; }
            offs[NN] = EE;
        }
        return;
    }
    __shared__ int sm[256];
    __shared__ int carry;
    __shared__ int tl[KK];
    if (t == 0) carry = 0;
    for (int i = t; i < MAXT; i += 256) tmap_b[i] = -1;
    __syncthreads();
    for (int c = 0; c < 7; ++c) {
        int i = c * 256 + t;
        int v = (i < NBC) ? nbc[i] : 0;
        sm[t] = v;
        __syncthreads();
        for (int off = 1; off < 256; off <<= 1) {
            int y = (t >= off) ? sm[t - off] : 0;
            __syncthreads();
            sm[t] += y;
            __syncthreads();
        }
        int base = carry;
        int excl = base + sm[t] - v;
        if (i < NBC) {
            gbase[i] = excl;
            if ((i % NB) == 0) koff[i / NB] = excl;
        }
        __syncthreads();
        if (t == 255) carry = base + sm[255];
        __syncthreads();
    }
    if (t == 0) {
        koff[KK] = NN;
        int run = 0;
        for (int k = 0; k < KK; ++k) {
            tl[k] = run;
            int cnt = ((k == KK - 1) ? NN : koff[k + 1]) - koff[k];
            run += (cnt + 63) / 64;
        }
    }
    __syncthreads();
    if (t < KK) {
        int k = t;
        int kb = koff[k];
        int ke = (k == KK - 1) ? NN : koff[k + 1];
        int nt = (ke - kb + 63) / 64;
        for (int tt = 0; tt < nt; ++tt) {
            tmap_b[tl[k] + tt] = k;
            tmap_s[tl[k] + tt] = kb + tt * 64;
        }
    }
}

// ================ K4: coarse_scatter (packed 4B edges) + nb_scatter ================
__global__ __launch_bounds__(256) void scatter_k(const int* __restrict__ src,
                                                 const int* __restrict__ dst,
                                                 int* __restrict__ bcur,
                                                 unsigned* __restrict__ ebuf,
                                                 const int* __restrict__ na,
                                                 const int* __restrict__ gbase,
                                                 int* __restrict__ perm) {
    __shared__ int s1[NB];
    __shared__ int s2[NB];
    const int t = threadIdx.x, b = blockIdx.x;
    if (b < GR1) {
        for (int i = t; i < NB; i += 256) s1[i] = 0;
        __syncthreads();
        const int base = b * BKE;
        unsigned mypk[8]; int mybin[8], myrank[8];
        #pragma unroll
        for (int u = 0; u < 8; ++u) {
            int e = base + t + u * 256;
            if (e < EE) {
                int d = dst[e];
                int s = src[e];
                mybin[u] = d >> 9;
                // pack: src (17b) | fine-bin (10b) << 17
                mypk[u] = (unsigned)s |
                          ((unsigned)(((d & 511) << 1) | (s < C0 ? 0 : 1)) << 17);
                myrank[u] = atomicAdd(&s1[mybin[u]], 1);
            } else mybin[u] = -1;
        }
        __syncthreads();
        for (int i = t; i < NB; i += 256) {
            int c = s1[i];
            s2[i] = c ? atomicAdd(&bcur[i], c) : 0;
        }
        __syncthreads();
        #pragma unroll
        for (int u = 0; u < 8; ++u) {
            if (mybin[u] >= 0) {
                ebuf[s2[mybin[u]] + myrank[u]] = mypk[u];
            }
        }
    } else {
        const int nb_ = b - GR1;
        if (t < KK) { s1[t] = 0; s2[t] = gbase[t * NB + nb_]; }
        __syncthreads();
        #pragma unroll
        for (int u = 0; u < 2; ++u) {
            int n = nb_ * 512 + t + u * 256;
            if (n < NN) {
                int k = na[n];
                int r = atomicAdd(&s1[k], 1);
                perm[s2[k] + r] = n;
            }
        }
    }
}

// ================ r2: per-bucket exact CSR (packed edges) ================
__global__ __launch_bounds__(256) void fine_scatter(const unsigned* __restrict__ ebuf,
                                                    const int* __restrict__ bbase,
                                                    const int* __restrict__ bend,
                                                    int* __restrict__ offs,
                                                    int* __restrict__ split,
                                                    int* __restrict__ ssrc) {
    __shared__ int hist[1024];
    __shared__ int lofs[1024];
    __shared__ int sm[256];
    const int t = threadIdx.x, b = blockIdx.x;
    const int beg = bbase[b], end = bend[b];
    for (int i = t; i < 1024; i += 256) hist[i] = 0;
    __syncthreads();
    for (int j = beg + t; j < end; j += 256) {
        unsigned pk = ebuf[j];
        atomicAdd(&hist[pk >> 17], 1);
    }
    __syncthreads();
    int v0 = hist[4 * t], v1 = hist[4 * t + 1], v2 = hist[4 * t + 2], v3 = hist[4 * t + 3];
    int ts = v0 + v1 + v2 + v3;
    sm[t] = ts;
    __syncthreads();
    for (int off = 1; off < 256; off <<= 1) {
        int y = (t >= off) ? sm[t - off] : 0;
        __syncthreads();
        sm[t] += y;
        __syncthreads();
    }
    int pre = sm[t] - ts;
    lofs[4 * t] = pre; lofs[4 * t + 1] = pre + v0;
    lofs[4 * t + 2] = pre + v0 + v1; lofs[4 * t + 3] = pre + v0 + v1 + v2;
    __syncthreads();
    const int d0 = b * 512;
    for (int i = t; i < 512; i += 256) {
        int n = d0 + i;
        if (n < NN) {
            offs[n]  = beg + lofs[2 * i];
            split[n] = beg + lofs[2 * i + 1];
        }
    }
    __syncthreads();
    for (int j = beg + t; j < end; j += 256) {
        unsigned pk = ebuf[j];
        int pos = beg + atomicAdd(&lofs[pk >> 17], 1);
        ssrc[pos] = (int)(pk & 0x1FFFFu);
    }
}

// ================ spmm v3: 8 lanes/node (16B each), 32 nodes/block, 8-deep ILP ================
// splt != nullptr -> gather only [beg, splt[n]) but normalize by full degree.
__global__ __launch_bounds__(256) void spmm(const ushortT* __restrict__ rows,
                                            const int* __restrict__ offs,
                                            const int* __restrict__ splt,
                                            const int* __restrict__ ssrc,
                                            ushortT* __restrict__ aggb) {
    const int t = threadIdx.x;
    const int g = t >> 3, c8 = t & 7;           // 32 nodes/block, 8 lanes/node
    const int n = blockIdx.x * 32 + g;
    const int beg = offs[n], endf = offs[n + 1];
    const int ge = splt ? splt[n] : endf;
    float a[8] = {}, c[8] = {};
    int j = beg;
    for (; j + 8 <= ge; j += 8) {
        int s0 = ssrc[j + 0], s1 = ssrc[j + 1], s2 = ssrc[j + 2], s3 = ssrc[j + 3];
        int s4 = ssrc[j + 4], s5 = ssrc[j + 5], s6 = ssrc[j + 6], s7 = ssrc[j + 7];
        uint4 v0 = *(const uint4*)(rows + (size_t)s0 * HID + c8 * 8);
        uint4 v1 = *(const uint4*)(rows + (size_t)s1 * HID + c8 * 8);
        uint4 v2 = *(const uint4*)(rows + (size_t)s2 * HID + c8 * 8);
        uint4 v3 = *(const uint4*)(rows + (size_t)s3 * HID + c8 * 8);
        uint4 v4 = *(const uint4*)(rows + (size_t)s4 * HID + c8 * 8);
        uint4 v5 = *(const uint4*)(rows + (size_t)s5 * HID + c8 * 8);
        uint4 v6 = *(const uint4*)(rows + (size_t)s6 * HID + c8 * 8);
        uint4 v7 = *(const uint4*)(rows + (size_t)s7 * HID + c8 * 8);
        acc8f(a, v0); acc8f(c, v1); acc8f(a, v2); acc8f(c, v3);
        acc8f(a, v4); acc8f(c, v5); acc8f(a, v6); acc8f(c, v7);
    }
    if (j + 4 <= ge) {
        int s0 = ssrc[j + 0], s1 = ssrc[j + 1], s2 = ssrc[j + 2], s3 = ssrc[j + 3];
        uint4 v0 = *(const uint4*)(rows + (size_t)s0 * HID + c8 * 8);
        uint4 v1 = *(const uint4*)(rows + (size_t)s1 * HID + c8 * 8);
        uint4 v2 = *(const uint4*)(rows + (size_t)s2 * HID + c8 * 8);
        uint4 v3 = *(const uint4*)(rows + (size_t)s3 * HID + c8 * 8);
        acc8f(a, v0); acc8f(c, v1); acc8f(a, v2); acc8f(c, v3);
        j += 4;
    }
    for (; j < ge; ++j) {
        uint4 v = *(const uint4*)(rows + (size_t)ssrc[j] * HID + c8 * 8);
        acc8f(a, v);
    }
    const float inv = 1.0f / fmaxf((float)(endf - beg), 1.0f);
    #pragma unroll
    for (int i = 0; i < 8; ++i) a[i] = (a[i] + c[i]) * inv;
    uint4 o;
    o.x = pk2(a[0], a[1]); o.y = pk2(a[2], a[3]);
    o.z = pk2(a[4], a[5]); o.w = pk2(a[6], a[7]);
    *(uint4*)(aggb + (size_t)n * HID + c8 * 8) = o;
}

// ================ shared 64x64x64 GEMM core ================
__device__ __forceinline__ void gemm64(const float As[64][65], const float Bs[64][64],
                                       float acc[4][4], int tx, int ty) {
    for (int kk = 0; kk < 64; ++kk) {
        float a0 = As[ty * 4 + 0][kk], a1 = As[ty * 4 + 1][kk];
        float a2 = As[ty * 4 + 2][kk], a3 = As[ty * 4 + 3][kk];
        float4 bv = *(const float4*)(&Bs[kk][tx * 4]);
        acc[0][0] += a0 * bv.x; acc[0][1] += a0 * bv.y; acc[0][2] += a0 * bv.z; acc[0][3] += a0 * bv.w;
        acc[1][0] += a1 * bv.x; acc[1][1] += a1 * bv.y; acc[1][2] += a1 * bv.z; acc[1][3] += a1 * bv.w;
        acc[2][0] += a2 * bv.x; acc[2][1] += a2 * bv.y; acc[2][2] += a2 * bv.z; acc[2][3] += a2 * bv.w;
        acc[3][0] += a3 * bv.x; acc[3][1] += a3 * bv.y; acc[3][2] += a3 * bv.z; acc[3][3] += a3 * bv.w;
    }
}

// ================ op GEMM: k-bucketed tiles, reads bf16 agg -> htb ================
__global__ __launch_bounds__(256) void op_gemm(const ushortT* __restrict__ aggb,
                                               const ushortT* __restrict__ hb,
                                               const int* __restrict__ perm,
                                               const int* __restrict__ koff,
                                               const int* __restrict__ tmap_b,
                                               const int* __restrict__ tmap_s,
                                               const float* __restrict__ op_W,
                                               const float* __restrict__ op_b,
                                               const float* __restrict__ emb_W,
                                               const float* __restrict__ emb_b,
                                               ushortT* __restrict__ htb) {
    __shared__ float As[64][65];
    __shared__ float Bs[64][64];
    __shared__ int idx[64];
    const int bk = tmap_b[blockIdx.x];
    if (bk < 0) return;
    const int start = tmap_s[blockIdx.x];
    const int kend = koff[bk + 1];
    const int tid = threadIdx.x;
    if (tid < 64) {
        int p = start + tid;
        idx[tid] = (p < kend) ? perm[p] : -1;
    }
    __syncthreads();
    for (int i = tid; i < 64 * 16; i += 256) {
        int r = i >> 4, c4 = i & 15;
        int n = idx[r];
        if (n >= 0) {
            ushort4 u = *(const ushort4*)(aggb + (size_t)n * HID + c4 * 4);
            As[r][c4 * 4 + 0] = b2f(u.x); As[r][c4 * 4 + 1] = b2f(u.y);
            As[r][c4 * 4 + 2] = b2f(u.z); As[r][c4 * 4 + 3] = b2f(u.w);
        } else {
            As[r][c4 * 4 + 0] = 0.f; As[r][c4 * 4 + 1] = 0.f;
            As[r][c4 * 4 + 2] = 0.f; As[r][c4 * 4 + 3] = 0.f;
        }
    }
    for (int i = tid; i < 64 * 16; i += 256) {
        int r = i >> 4, c4 = i & 15;
        *(float4*)(&Bs[r][c4 * 4]) = *(const float4*)(op_W + (size_t)bk * HID * HID + (size_t)r * HID + c4 * 4);
    }
    __syncthreads();
    const int tx = tid & 15, ty = tid >> 4;
    float acc[4][4] = {};
    gemm64(As, Bs, acc, tx, ty);
    float4 ob = *(const float4*)(op_b + (size_t)bk * HID + tx * 4);
    #pragma unroll
    for (int rr = 0; rr < 4; ++rr) {
        int n = idx[ty * 4 + rr];
        if (n < 0) continue;
        float4 v;
        v.x = acc[rr][0] + ob.x; v.y = acc[rr][1] + ob.y;
        v.z = acc[rr][2] + ob.z; v.w = acc[rr][3] + ob.w;
        if (n < C0) {
            ushort4 hu = *(const ushort4*)(hb + (size_t)n * HID + tx * 4);
            v.x += b2f(hu.x); v.y += b2f(hu.y); v.z += b2f(hu.z); v.w += b2f(hu.w);
        } else {
            int si = (n < C0 + C1) ? 0 : 1;
            int rn = n - C0 - si * C1;
            float4 ew = *(const float4*)(emb_W + ((size_t)si * C1 + rn) * HID + tx * 4);
            float4 eb = *(const float4*)(emb_b + (size_t)si * HID + tx * 4);
            v.x += ew.x + eb.x; v.y += ew.y + eb.y;
            v.z += ew.z + eb.z; v.w += ew.w + eb.w;
        }
        ushort4 o;
        o.x = f2b(v.x); o.y = f2b(v.y); o.z = f2b(v.z); o.w = f2b(v.w);
        *(ushort4*)(htb + (size_t)n * HID + tx * 4) = o;
    }
}

// ================ fc GEMM: contiguous segment rows, in-place htb ================
__global__ __launch_bounds__(256) void fc_gemm(ushortT* __restrict__ htb,
                                               const float* __restrict__ fc_W,
                                               const float* __restrict__ fc_b) {
    __shared__ float As[64][65];
    __shared__ float Bs[64][64];
    const int si = (blockIdx.x < FCT) ? 0 : 1;
    const int t0 = blockIdx.x - si * FCT;
    const int row0 = C0 + si * C1 + t0 * 64;
    const int lim = C0 + (si + 1) * C1;
    const int tid = threadIdx.x;
    for (int i = tid; i < 64 * 16; i += 256) {
        int r = i >> 4, c4 = i & 15;
        int n = row0 + r;
        if (n < lim) {
            ushort4 u = *(const ushort4*)(htb + (size_t)n * HID + c4 * 4);
            As[r][c4 * 4 + 0] = b2f(u.x); As[r][c4 * 4 + 1] = b2f(u.y);
            As[r][c4 * 4 + 2] = b2f(u.z); As[r][c4 * 4 + 3] = b2f(u.w);
        } else {
            As[r][c4 * 4 + 0] = 0.f; As[r][c4 * 4 + 1] = 0.f;
            As[r][c4 * 4 + 2] = 0.f; As[r][c4 * 4 + 3] = 0.f;
        }
    }
    for (int i = tid; i < 64 * 16; i += 256) {
        int r = i >> 4, c4 = i & 15;
        *(float4*)(&Bs[r][c4 * 4]) = *(const float4*)(fc_W + (size_t)si * HID * HID + (size_t)r * HID + c4 * 4);
    }
    __syncthreads();
    const int tx = tid & 15, ty = tid >> 4;
    float acc[4][4] = {};
    gemm64(As, Bs, acc, tx, ty);
    float4 fb = *(const float4*)(fc_b + (size_t)si * HID + tx * 4);
    #pragma unroll
    for (int rr = 0; rr < 4; ++rr) {
        int n = row0 + ty * 4 + rr;
        if (n >= lim) continue;
        ushort4 o;
        o.x = f2b(acc[rr][0] + fb.x); o.y = f2b(acc[rr][1] + fb.y);
        o.z = f2b(acc[rr][2] + fb.z); o.w = f2b(acc[rr][3] + fb.w);
        *(ushort4*)(htb + (size_t)n * HID + tx * 4) = o;
    }
}

// ================ gnn GEMM + elu + logits (reads bf16 agg) ================
__global__ __launch_bounds__(256) void gnn_logits(const ushortT* __restrict__ aggb,
                                                  const float* __restrict__ gnn_W,
                                                  const float* __restrict__ gnn_b,
                                                  const float* __restrict__ out_W,
                                                  const float* __restrict__ out_b,
                                                  float* __restrict__ out) {
    __shared__ float As[64][65];
    __shared__ float Bs[64][64];
    __shared__ float Wo[64 * NCLS];
    const int row0 = blockIdx.x * 64;
    const int tid = threadIdx.x;
    for (int i = tid; i < 64 * 16; i += 256) {
        int r = i >> 4, c4 = i & 15;
        int n = row0 + r;
        if (n < NN) {
            ushort4 u = *(const ushort4*)(aggb + (size_t)n * HID + c4 * 4);
            As[r][c4 * 4 + 0] = b2f(u.x); As[r][c4 * 4 + 1] = b2f(u.y);
            As[r][c4 * 4 + 2] = b2f(u.z); As[r][c4 * 4 + 3] = b2f(u.w);
        } else {
            As[r][c4 * 4 + 0] = 0.f; As[r][c4 * 4 + 1] = 0.f;
            As[r][c4 * 4 + 2] = 0.f; As[r][c4 * 4 + 3] = 0.f;
        }
    }
    for (int i = tid; i < 64 * 16; i += 256) {
        int r = i >> 4, c4 = i & 15;
        *(float4*)(&Bs[r][c4 * 4]) = *(const float4*)(gnn_W + (size_t)r * HID + c4 * 4);
    }
    *(float4*)(&Wo[tid * 4]) = *(const float4*)(out_W + tid * 4);
    __syncthreads();
    const int tx = tid & 15, ty = tid >> 4;
    float acc[4][4] = {};
    gemm64(As, Bs, acc, tx, ty);
    __syncthreads();     // done reading As; reuse for emb
    float4 gb = *(const float4*)(gnn_b + tx * 4);
    #pragma unroll
    for (int rr = 0; rr < 4; ++rr) {
        int n = row0 + ty * 4 + rr;
        float4 v;
        v.x = acc[rr][0] + gb.x; v.y = acc[rr][1] + gb.y;
        v.z = acc[rr][2] + gb.z; v.w = acc[rr][3] + gb.w;
        v.x = (v.x > 0.f) ? v.x : expm1f(v.x);
        v.y = (v.y > 0.f) ? v.y : expm1f(v.y);
        v.z = (v.z > 0.f) ? v.z : expm1f(v.z);
        v.w = (v.w > 0.f) ? v.w : expm1f(v.w);
        As[ty * 4 + rr][tx * 4 + 0] = v.x; As[ty * 4 + rr][tx * 4 + 1] = v.y;
        As[ty * 4 + rr][tx * 4 + 2] = v.z; As[ty * 4 + rr][tx * 4 + 3] = v.w;
        if (n < NN) *(float4*)(out + (size_t)n * HID + tx * 4) = v;
    }
    __syncthreads();
    const int r = tid >> 2, cq = (tid & 3) * 4;
    float l0 = 0.f, l1 = 0.f, l2 = 0.f, l3 = 0.f;
    #pragma unroll 8
    for (int j = 0; j < 64; ++j) {
        float e = As[r][j];
        float4 w = *(const float4*)(&Wo[j * NCLS + cq]);
        l0 += e * w.x; l1 += e * w.y; l2 += e * w.z; l3 += e * w.w;
    }
    int n = row0 + r;
    if (n < NN) {
        float4 ob = *(const float4*)(out_b + cq);
        float4 lg;
        lg.x = l0 + ob.x; lg.y = l1 + ob.y; lg.z = l2 + ob.z; lg.w = l3 + ob.w;
        const size_t lbase = (size_t)NN * HID;
        *(float4*)(out + lbase + (size_t)n * NCLS + cq) = lg;
        *(float4*)(out + lbase + (size_t)NN * NCLS + (size_t)n * NCLS + cq) = lg;
    }
}

extern "C" void kernel_launch(void* const* d_in, const int* in_sizes, int n_in,
                              void* d_out, int out_size, void* d_ws, size_t ws_size,
                              hipStream_t stream) {
    const float* feats0 = (const float*)d_in[0];
    const float* W_pre  = (const float*)d_in[1];
    const float* b_pre  = (const float*)d_in[2];
    const float* emb_W  = (const float*)d_in[3];
    const float* emb_b  = (const float*)d_in[4];
    const float* op_W   = (const float*)d_in[5];
    const float* op_b   = (const float*)d_in[6];
    const float* fc_W   = (const float*)d_in[7];
    const float* fc_b   = (const float*)d_in[8];
    const float* gnn_W  = (const float*)d_in[9];
    const float* gnn_b  = (const float*)d_in[10];
    const float* out_W  = (const float*)d_in[11];
    const float* out_b  = (const float*)d_in[12];
    const int* src         = (const int*)d_in[13];
    const int* dst         = (const int*)d_in[14];
    const int* node_assign = (const int*)d_in[15];
    float* out = (float*)d_out;

    // workspace layout (~38 MB). aggb (12.8MB) aliases ebuf (6.4MB packed) —
    // ebuf dead after fine_scatter; aggb written by spmm1, consumed by op_gemm,
    // rewritten by spmm2, consumed by gnn_logits.
    ushortT* hb  = (ushortT*)d_ws;                     // C0*HID bf16
    ushortT* htb = hb + (size_t)C0 * HID;              // NN*HID bf16
    ushortT* aggb = htb + (size_t)NN * HID;            // NN*HID bf16 (12.8 MB union)
    unsigned* ebuf = (unsigned*)aggb;                  // EE u32 (6.4 MB, alias)
    ushortT* WT = aggb + (size_t)NN * HID;             // 64*512 bf16
    int* ssrc   = (int*)(WT + (size_t)HID * DIN);      // EE
    int* offs   = ssrc + EE;                           // NN+1
    int* split  = offs + NN + 1;                       // NN
    int* perm   = split + NN;                          // NN
    int* nbc    = perm + NN;                           // NBC
    int* gbase  = nbc + NBC;                           // NBC
    int* koff   = gbase + NBC;                         // KK+1
    int* tmap_b = koff + KK + 1;                       // MAXT
    int* tmap_s = tmap_b + MAXT;                       // MAXT
    int* bcnt   = tmap_s + MAXT;                       // NB
    int* bbase  = bcnt + NB;                           // NB
    int* bcur   = bbase + NB;                          // NB

    hipMemsetAsync(bcnt, 0, NB * sizeof(int), stream);

    setup_k<<<GR1 + NB + 16, 256, 0, stream>>>(dst, node_assign, W_pre, bcnt, nbc, WT);
    pre_mfma<<<C0 / 64, 256, 0, stream>>>(feats0, WT, b_pre, hb);
    scan_k<<<2, 256, 0, stream>>>(bcnt, bbase, bcur, offs, nbc, gbase, koff, tmap_b, tmap_s);
    scatter_k<<<GR1 + NB, 256, 0, stream>>>(src, dst, bcur, ebuf, node_assign, gbase, perm);
    fine_scatter<<<NB, 256, 0, stream>>>(ebuf, bbase, bcur, offs, split, ssrc);
    spmm<<<NN / 32, 256, 0, stream>>>(hb, offs, split, ssrc, aggb);          // filtered
    op_gemm<<<MAXT, 256, 0, stream>>>(aggb, hb, perm, koff, tmap_b, tmap_s,
                                      op_W, op_b, emb_W, emb_b, htb);
    fc_gemm<<<2 * FCT, 256, 0, stream>>>(htb, fc_W, fc_b);
    spmm<<<NN / 32, 256, 0, stream>>>(htb, offs, nullptr, ssrc, aggb);       // full
    gnn_logits<<<GNT, 256, 0, stream>>>(aggb, gnn_W, gnn_b, out_W, out_b, out);
}